// Round 4
// baseline (375.311 us; speedup 1.0000x reference)
//
#include <hip/hip_runtime.h>
#include <hip/hip_fp16.h>
#include <math.h>

#define HW 65536               // 256*256

typedef float v2f __attribute__((ext_vector_type(2), aligned(8)));
typedef _Float16 h2 __attribute__((ext_vector_type(2)));

__device__ __forceinline__ h2 uh(unsigned u) { return __builtin_bit_cast(h2, u); }

#define CEH(a, b) { h2 _t = __builtin_elementwise_min(a, b); \
                    b = __builtin_elementwise_max(a, b); a = _t; }

__device__ __forceinline__ void sort8_h2(h2* v) {
    CEH(v[0], v[1]); CEH(v[2], v[3]); CEH(v[4], v[5]); CEH(v[6], v[7]);
    CEH(v[0], v[2]); CEH(v[1], v[3]); CEH(v[4], v[6]); CEH(v[5], v[7]);
    CEH(v[1], v[2]); CEH(v[5], v[6]); CEH(v[0], v[4]); CEH(v[3], v[7]);
    CEH(v[1], v[5]); CEH(v[2], v[6]);
    CEH(v[1], v[4]); CEH(v[3], v[6]);
    CEH(v[2], v[4]); CEH(v[3], v[5]);
    CEH(v[3], v[4]);
}
__device__ __forceinline__ void sort4_h2(h2* v) {
    CEH(v[0], v[1]); CEH(v[2], v[3]); CEH(v[0], v[2]); CEH(v[1], v[3]); CEH(v[1], v[2]);
}

// ---------------- K0: pack per-(c,i) weights as fp16 {w,w} u32 pairs ----------------
// wtab[(c*4+i)*16 + j]: j0..2 = l1w[0..2], j3 = 2*l1w[3], j4 = l1b,
//                       j5..12 = l2w[0..7], j13 = l2b.  wtab[1024 + c*4 + k] = bw.
__global__ __launch_bounds__(256) void k_pack(const float* __restrict__ l1w,
                                              const float* __restrict__ l1b,
                                              const float* __restrict__ l2w,
                                              const float* __restrict__ l2b,
                                              const float* __restrict__ bw,
                                              unsigned* __restrict__ wtab) {
    for (int t = threadIdx.x; t < 1088; t += 256) {
        float v = 0.f;
        if (t < 1024) {
            int c = t >> 6, i = (t >> 4) & 3, j = t & 15;
            if (j < 3)        v = l1w[i * 64 + c * 4 + j];
            else if (j == 3)  v = 2.f * l1w[i * 64 + c * 4 + 3];
            else if (j == 4)  v = l1b[i * 16 + c];
            else if (j < 13)  v = l2w[i * 128 + c * 8 + (j - 5)];
            else if (j == 13) v = l2b[i * 16 + c];
        } else {
            v = bw[t - 1024];
        }
        unsigned hs = (unsigned)__half_as_ushort(__float2half(v));
        wtab[t] = hs * 0x10001u;
    }
}

// ---------------- K1: in_conv 1x1, 64 -> 16, 4-px float4, LDS weights, fp16 out ----------------
__global__ __launch_bounds__(256, 4) void k_inconv(const float* __restrict__ cen,
                                                   const float* __restrict__ w,
                                                   const float* __restrict__ bias,
                                                   __half* __restrict__ xh) {
    __shared__ float wl[1040];   // wl[i*16+o] = w[o*64+i], + bias at 1024
    int tid = threadIdx.x;
    for (int t = tid; t < 1024; t += 256) wl[t] = w[(t & 15) * 64 + (t >> 4)];
    if (tid < 16) wl[1024 + tid] = bias[tid];
    __syncthreads();

    int q  = blockIdx.x * 256 + tid;      // quad index, 0..131071
    int b_ = q >> 14;                     // 16384 quads per image
    int hw = (q & 16383) * 4;
    const float* src = cen + (size_t)(b_ * 64) * HW + hw;

    float4 acc[16];
#pragma unroll
    for (int o = 0; o < 16; o++) { float bv = wl[1024 + o]; acc[o] = make_float4(bv, bv, bv, bv); }

#pragma unroll 4
    for (int i = 0; i < 64; i++) {
        float4 xv = *(const float4*)(src + (size_t)i * HW);
        const float4* wq = (const float4*)&wl[i * 16];   // uniform -> ds broadcast
#pragma unroll
        for (int g = 0; g < 4; g++) {
            float4 f = wq[g];
            acc[g * 4 + 0].x += xv.x * f.x; acc[g * 4 + 0].y += xv.y * f.x;
            acc[g * 4 + 0].z += xv.z * f.x; acc[g * 4 + 0].w += xv.w * f.x;
            acc[g * 4 + 1].x += xv.x * f.y; acc[g * 4 + 1].y += xv.y * f.y;
            acc[g * 4 + 1].z += xv.z * f.y; acc[g * 4 + 1].w += xv.w * f.y;
            acc[g * 4 + 2].x += xv.x * f.z; acc[g * 4 + 2].y += xv.y * f.z;
            acc[g * 4 + 2].z += xv.z * f.z; acc[g * 4 + 2].w += xv.w * f.z;
            acc[g * 4 + 3].x += xv.x * f.w; acc[g * 4 + 3].y += xv.y * f.w;
            acc[g * 4 + 3].z += xv.z * f.w; acc[g * 4 + 3].w += xv.w * f.w;
        }
    }
    __half* dst = xh + (size_t)(b_ * 16) * HW + hw;
#pragma unroll
    for (int o = 0; o < 16; o++) {
        uint2 pk;
        pk.x = __builtin_bit_cast(unsigned, __floats2half2_rn(acc[o].x, acc[o].y));
        pk.y = __builtin_bit_cast(unsigned, __floats2half2_rn(acc[o].z, acc[o].w));
        *(uint2*)(dst + (size_t)o * HW) = pk;
    }
}

// ---------------- K2: FUSED depthwise convs + machinery, one (32x32 tile, b, c) per block ----
// grid (64, 128): x = tile (8x8), y = b*16 + c.  512 threads.
// Stage 52x52 x-tile (fp16 global -> fp32 LDS), compute 4 convs in-LDS into
// convt[4][46 rows][24 dwords] (zero outside image), then per-pixel-pair machinery.
__global__ __launch_bounds__(512, 4) void k_fused(const __half* __restrict__ xh,
    const float* __restrict__ dw_w1, const float* __restrict__ dw_b1,
    const float* __restrict__ dw_w3, const float* __restrict__ dw_b3,
    const float* __restrict__ dw_w5, const float* __restrict__ dw_b5,
    const float* __restrict__ dw_w7, const float* __restrict__ dw_b7,
    const unsigned* __restrict__ wtab,
    const float* __restrict__ bns, const float* __restrict__ bnb,
    __half* __restrict__ y16) {

    const int by  = blockIdx.y;                  // b*16 + c
    const int c   = by & 15;
    const int ty0 = (blockIdx.x >> 3) * 32;      // tile origin (image coords)
    const int tx0 = (blockIdx.x & 7) * 32;
    const int tid = threadIdx.x;

    __shared__ float lx[52 * 56];                        // x rows/cols ty0-10..+41 (52x52 used)
    __shared__ __align__(16) unsigned convt[4 * 46 * 24];  // conv planes, rows ty0-7..+38

    // ---- stage x tile: 52 rows x 13 uint2 (4 halves) ----
    const __half* xp = xh + (size_t)by * HW;
    for (int t = tid; t < 676; t += 512) {
        int r = t / 13, d = t - r * 13;
        int gy = ty0 - 10 + r, gx0 = tx0 - 10 + 4 * d;
        float a0 = 0.f, a1 = 0.f, a2 = 0.f, a3 = 0.f;
        if ((unsigned)gy < 256u) {
            const __half* rp = xp + gy * 256;
            if (gx0 >= 0 && gx0 <= 252) {
                uint2 u = *(const uint2*)(rp + gx0);
                float2 f0 = __half22float2(__builtin_bit_cast(__half2, u.x));
                float2 f1 = __half22float2(__builtin_bit_cast(__half2, u.y));
                a0 = f0.x; a1 = f0.y; a2 = f1.x; a3 = f1.y;
            } else {
                if ((unsigned)(gx0 + 0) < 256u) a0 = __half2float(rp[gx0 + 0]);
                if ((unsigned)(gx0 + 1) < 256u) a1 = __half2float(rp[gx0 + 1]);
                if ((unsigned)(gx0 + 2) < 256u) a2 = __half2float(rp[gx0 + 2]);
                if ((unsigned)(gx0 + 3) < 256u) a3 = __half2float(rp[gx0 + 3]);
            }
        }
        *(float4*)&lx[r * 56 + 4 * d] = make_float4(a0, a1, a2, a3);
    }
    __syncthreads();

    // ---- depthwise convs: 46 rows x 23 col-pairs, 2-px packed ----
    {
        const float* W7 = dw_w7 + c * 49;
        const float* W5 = dw_w5 + c * 25;
        const float* W3 = dw_w3 + c * 9;
        const float  W1 = dw_w1[c];
        const float  B1 = dw_b1[c], B3 = dw_b3[c], B5 = dw_b5[c], B7 = dw_b7[c];

        for (int u = tid; u < 46 * 23; u += 512) {
            int row = u / 23;
            int pc0 = (u - row * 23) * 2;
            v2f c7v = {0, 0}, c5v = {0, 0}, c3v = {0, 0}, c1v = {0, 0};
#pragma unroll
            for (int a = 0; a < 7; a++) {
                const float* rp = &lx[(row + a) * 56 + pc0];
                v2f q0 = *(const v2f*)rp;
                v2f q1 = *(const v2f*)(rp + 2);
                v2f q2 = *(const v2f*)(rp + 4);
                v2f q3 = *(const v2f*)(rp + 6);
                float v[8] = {q0.x, q0.y, q1.x, q1.y, q2.x, q2.y, q3.x, q3.y};
#pragma unroll
                for (int bb = 0; bb < 7; bb++) {
                    v2f vv = {v[bb], v[bb + 1]};
                    c7v += vv * W7[a * 7 + bb];
                }
                if (a >= 1 && a <= 5) {
#pragma unroll
                    for (int bb = 0; bb < 5; bb++) {
                        v2f vv = {v[bb + 1], v[bb + 2]};
                        c5v += vv * W5[(a - 1) * 5 + bb];
                    }
                }
                if (a >= 2 && a <= 4) {
#pragma unroll
                    for (int bb = 0; bb < 3; bb++) {
                        v2f vv = {v[bb + 2], v[bb + 3]};
                        c3v += vv * W3[(a - 2) * 3 + bb];
                    }
                }
                if (a == 3) {
                    v2f vv = {v[3], v[4]};
                    c1v = vv * W1;
                }
            }
            int iy = ty0 - 7 + row, ix = tx0 - 7 + pc0;
            bool rin = (unsigned)iy < 256u;
            bool in0 = rin && (unsigned)ix < 256u;
            bool in1 = rin && (unsigned)(ix + 1) < 256u;
            int o = row * 24 + (pc0 >> 1);
            convt[o]        = __builtin_bit_cast(unsigned, __floats2half2_rn(in0 ? c1v.x + B1 : 0.f, in1 ? c1v.y + B1 : 0.f));
            convt[o + 1104] = __builtin_bit_cast(unsigned, __floats2half2_rn(in0 ? c3v.x + B3 : 0.f, in1 ? c3v.y + B3 : 0.f));
            convt[o + 2208] = __builtin_bit_cast(unsigned, __floats2half2_rn(in0 ? c5v.x + B5 : 0.f, in1 ? c5v.y + B5 : 0.f));
            convt[o + 3312] = __builtin_bit_cast(unsigned, __floats2half2_rn(in0 ? c7v.x + B7 : 0.f, in1 ? c7v.y + B7 : 0.f));
        }
    }
    __syncthreads();

    // ---- machinery: one horizontal pixel pair per thread ----
    const int py  = tid >> 4;                    // 0..31
    const int pxp = tid & 15;                    // pair within row

    h2 bh[4];
#pragma unroll
    for (int i = 0; i < 4; i++) {
        const int s = 1 + 2 * i;
        const unsigned* pl = convt + i * 1104;
        const int q    = pxp + (7 - s) / 2;          // start dword within row
        const int topb = (py + 7 - s) * 24 + q;
        const int midb = (py + 7) * 24 + q;
        const int botb = (py + 7 + s) * 24 + q;

        unsigned tt[8], tm[8], tb[8];
#pragma unroll
        for (int k = 0; k <= s; k++) {
            tt[k] = pl[topb + k];
            tm[k] = pl[midb + k];
            tb[k] = pl[botb + k];
        }
        const int m = s >> 1;   // (s-1)/2
        h2 n0  = uh(tt[0]);
        h2 n1  = uh((tt[m] >> 16) | (tt[m + 1] << 16));
        h2 n2  = uh(tt[s]);
        h2 n7  = uh(tm[0]);
        h2 ctr = uh((tm[m] >> 16) | (tm[m + 1] << 16));
        h2 n3  = uh(tm[s]);
        h2 n6  = uh(tb[0]);
        h2 n5  = uh((tb[m] >> 16) | (tb[m + 1] << 16));
        h2 n4  = uh(tb[s]);

        h2 T[8];
        T[0] = ctr - n0; T[1] = ctr - n1; T[2] = ctr - n2; T[3] = ctr - n3;
        T[4] = ctr - n4; T[5] = ctr - n5; T[6] = ctr - n6; T[7] = ctr - n7;
        h2 S[4];
#pragma unroll
        for (int k = 0; k < 4; k++) S[k] = T[k] + T[k + 4];

        const unsigned* wt = wtab + ((c << 2) + i) * 16;   // block-uniform -> s_load
        h2 w10 = uh(wt[0]), w11 = uh(wt[1]), w12 = uh(wt[2]);
        h2 w13x2 = uh(wt[3]), bb1 = uh(wt[4]);

        h2 R[4];
#pragma unroll
        for (int mm = 0; mm < 4; mm++) {
            h2 r = S[(mm + 2) & 3] * w12 + bb1;
            r = S[(mm + 3) & 3] * w11 + r;
            r = S[(mm + 1) & 3] * w10 + r;
            R[mm] = r;
        }
        h2 h8[8];
#pragma unroll
        for (int k = 0; k < 8; k++)
            h8[k] = (T[(k + 4) & 7] * w13x2 + R[k & 3]) * T[k];
        sort8_h2(h8);

        h2 acc = uh(wt[13]);
#pragma unroll
        for (int k = 0; k < 8; k++) acc += h8[k] * uh(wt[5 + k]);
        bh[i] = acc;
    }
    sort4_h2(bh);
    h2 yv = bh[0] * uh(wtab[1024 + (c << 2)]);
#pragma unroll
    for (int k = 1; k < 4; k++) yv = bh[k] * uh(wtab[1024 + (c << 2) + k]) + yv;

    const float bsc = bns[c], bbi = bnb[c];      // block-uniform -> s_load
    float zx = fmaf((float)yv.x, bsc, bbi);
    float zy = fmaf((float)yv.y, bsc, bbi);
    float sx = zx / (1.f + __expf(-zx));
    float sy = zy / (1.f + __expf(-zy));
    *(__half2*)&y16[(size_t)by * HW + (ty0 + py) * 256 + tx0 + 2 * pxp] =
        __floats2half2_rn(sx, sy);
}

// ---------------- K3: final 1x1 16 -> 1 + sigmoid ----------------
__global__ __launch_bounds__(256) void k_final(const __half* __restrict__ y16,
                                               const float* __restrict__ fw,
                                               const float* __restrict__ fb,
                                               float* __restrict__ out) {
    long t  = (long)blockIdx.x * 256 + threadIdx.x;   // pair index
    long p0 = t * 2;
    int  b  = (int)(p0 >> 16);
    int  hw = (int)(p0 & 65535);

    float accx = fb[0], accy = fb[0];
#pragma unroll
    for (int cc = 0; cc < 16; cc++) {
        __half2 h = *(const __half2*)(y16 + (size_t)(b * 16 + cc) * HW + hw);
        float2 v = __half22float2(h);
        float wv = fw[cc];
        accx = fmaf(v.x, wv, accx);
        accy = fmaf(v.y, wv, accy);
    }
    float2 r;
    r.x = 1.f / (1.f + __expf(-accx));
    r.y = 1.f / (1.f + __expf(-accy));
    *(float2*)(out + p0) = r;
}

extern "C" void kernel_launch(void* const* d_in, const int* in_sizes, int n_in,
                              void* d_out, int out_size, void* d_ws, size_t ws_size,
                              hipStream_t stream) {
    (void)in_sizes; (void)n_in; (void)out_size; (void)ws_size;
    const float* cen   = (const float*)d_in[0];
    // d_in[1] = mas (unused by the reference)
    const float* in_w  = (const float*)d_in[2];
    const float* in_b  = (const float*)d_in[3];
    const float* dw_w1 = (const float*)d_in[4];
    const float* dw_b1 = (const float*)d_in[5];
    const float* dw_w3 = (const float*)d_in[6];
    const float* dw_b3 = (const float*)d_in[7];
    const float* dw_w5 = (const float*)d_in[8];
    const float* dw_b5 = (const float*)d_in[9];
    const float* dw_w7 = (const float*)d_in[10];
    const float* dw_b7 = (const float*)d_in[11];
    const float* l1w   = (const float*)d_in[12];
    const float* l1b   = (const float*)d_in[13];
    const float* l2w   = (const float*)d_in[14];
    const float* l2b   = (const float*)d_in[15];
    const float* bw    = (const float*)d_in[16];
    const float* bns   = (const float*)d_in[17];
    const float* bnb   = (const float*)d_in[18];
    const float* fw    = (const float*)d_in[19];
    const float* fb    = (const float*)d_in[20];

    // workspace: xh (16.78 MB) | wtab (8 KB) | y16 (16.78 MB)
    __half*   xh   = (__half*)d_ws;
    unsigned* wtab = (unsigned*)((char*)d_ws + (size_t)16777216);
    __half*   y16  = (__half*)((char*)d_ws + (size_t)16777216 + 8192);
    float*    out  = (float*)d_out;

    k_pack<<<1, 256, 0, stream>>>(l1w, l1b, l2w, l2b, bw, wtab);
    k_inconv<<<512, 256, 0, stream>>>(cen, in_w, in_b, xh);
    k_fused<<<dim3(64, 128), 512, 0, stream>>>(xh, dw_w1, dw_b1, dw_w3, dw_b3,
                                               dw_w5, dw_b5, dw_w7, dw_b7,
                                               wtab, bns, bnb, y16);
    k_final<<<1024, 256, 0, stream>>>(y16, fw, fb, out);
}

// Round 5
// 359.062 us; speedup vs baseline: 1.0453x; 1.0453x over previous
//
#include <hip/hip_runtime.h>
#include <hip/hip_fp16.h>
#include <math.h>

#define HW 65536               // 256*256

typedef float v2f __attribute__((ext_vector_type(2), aligned(8)));
typedef _Float16 h2 __attribute__((ext_vector_type(2)));

__device__ __forceinline__ h2 uh(unsigned u) { return __builtin_bit_cast(h2, u); }
__device__ __forceinline__ unsigned hu(h2 v) { return __builtin_bit_cast(unsigned, v); }

#define CEH(a, b) { h2 _t = __builtin_elementwise_min(a, b); \
                    b = __builtin_elementwise_max(a, b); a = _t; }

__device__ __forceinline__ void sort8_h2(h2* v) {
    CEH(v[0], v[1]); CEH(v[2], v[3]); CEH(v[4], v[5]); CEH(v[6], v[7]);
    CEH(v[0], v[2]); CEH(v[1], v[3]); CEH(v[4], v[6]); CEH(v[5], v[7]);
    CEH(v[1], v[2]); CEH(v[5], v[6]); CEH(v[0], v[4]); CEH(v[3], v[7]);
    CEH(v[1], v[5]); CEH(v[2], v[6]);
    CEH(v[1], v[4]); CEH(v[3], v[6]);
    CEH(v[2], v[4]); CEH(v[3], v[5]);
    CEH(v[3], v[4]);
}
__device__ __forceinline__ void sort4_h2(h2* v) {
    CEH(v[0], v[1]); CEH(v[2], v[3]); CEH(v[0], v[2]); CEH(v[1], v[3]); CEH(v[1], v[2]);
}

// ---------------- K0: pack weights as fp16 {w,w} u32 pairs ----------------
// [0..1023]   machinery per-(c,i): j0..2=l1w, j3=2*l1w[3], j4=l1b, j5..12=l2w, j13=l2b
// [1024..1087] bw
// [2048+c*96 ..]: j0..48=w7, 49..73=w5, 74..82=w3, 83=w1, 84..87=B1,B3,B5,B7
__global__ __launch_bounds__(256) void k_pack(const float* __restrict__ l1w,
                                              const float* __restrict__ l1b,
                                              const float* __restrict__ l2w,
                                              const float* __restrict__ l2b,
                                              const float* __restrict__ bw,
                                              const float* __restrict__ dw_w1,
                                              const float* __restrict__ dw_b1,
                                              const float* __restrict__ dw_w3,
                                              const float* __restrict__ dw_b3,
                                              const float* __restrict__ dw_w5,
                                              const float* __restrict__ dw_b5,
                                              const float* __restrict__ dw_w7,
                                              const float* __restrict__ dw_b7,
                                              unsigned* __restrict__ wtab) {
    for (int t = threadIdx.x; t < 3584; t += 256) {
        float v = 0.f;
        if (t < 1024) {
            int c = t >> 6, i = (t >> 4) & 3, j = t & 15;
            if (j < 3)        v = l1w[i * 64 + c * 4 + j];
            else if (j == 3)  v = 2.f * l1w[i * 64 + c * 4 + 3];
            else if (j == 4)  v = l1b[i * 16 + c];
            else if (j < 13)  v = l2w[i * 128 + c * 8 + (j - 5)];
            else if (j == 13) v = l2b[i * 16 + c];
        } else if (t < 1088) {
            v = bw[t - 1024];
        } else if (t >= 2048) {
            int c = (t - 2048) / 96, j = (t - 2048) - c * 96;
            if (j < 49)       v = dw_w7[c * 49 + j];
            else if (j < 74)  v = dw_w5[c * 25 + (j - 49)];
            else if (j < 83)  v = dw_w3[c * 9 + (j - 74)];
            else if (j == 83) v = dw_w1[c];
            else if (j == 84) v = dw_b1[c];
            else if (j == 85) v = dw_b3[c];
            else if (j == 86) v = dw_b5[c];
            else if (j == 87) v = dw_b7[c];
        }
        unsigned hs = (unsigned)__half_as_ushort(__float2half(v));
        wtab[t] = hs * 0x10001u;
    }
}

// ---------------- K1: in_conv 1x1, 64 -> 16, 4-px float4, LDS weights, fp16 out ----------------
__global__ __launch_bounds__(256, 4) void k_inconv(const float* __restrict__ cen,
                                                   const float* __restrict__ w,
                                                   const float* __restrict__ bias,
                                                   __half* __restrict__ xh) {
    __shared__ float wl[1040];   // wl[i*16+o] = w[o*64+i], + bias at 1024
    int tid = threadIdx.x;
    for (int t = tid; t < 1024; t += 256) wl[t] = w[(t & 15) * 64 + (t >> 4)];
    if (tid < 16) wl[1024 + tid] = bias[tid];
    __syncthreads();

    int q  = blockIdx.x * 256 + tid;      // quad index, 0..131071
    int b_ = q >> 14;                     // 16384 quads per image
    int hw = (q & 16383) * 4;
    const float* src = cen + (size_t)(b_ * 64) * HW + hw;

    float4 acc[16];
#pragma unroll
    for (int o = 0; o < 16; o++) { float bv = wl[1024 + o]; acc[o] = make_float4(bv, bv, bv, bv); }

#pragma unroll 4
    for (int i = 0; i < 64; i++) {
        float4 xv = *(const float4*)(src + (size_t)i * HW);
        const float4* wq = (const float4*)&wl[i * 16];   // uniform -> ds broadcast
#pragma unroll
        for (int g = 0; g < 4; g++) {
            float4 f = wq[g];
            acc[g * 4 + 0].x += xv.x * f.x; acc[g * 4 + 0].y += xv.y * f.x;
            acc[g * 4 + 0].z += xv.z * f.x; acc[g * 4 + 0].w += xv.w * f.x;
            acc[g * 4 + 1].x += xv.x * f.y; acc[g * 4 + 1].y += xv.y * f.y;
            acc[g * 4 + 1].z += xv.z * f.y; acc[g * 4 + 1].w += xv.w * f.y;
            acc[g * 4 + 2].x += xv.x * f.z; acc[g * 4 + 2].y += xv.y * f.z;
            acc[g * 4 + 2].z += xv.z * f.z; acc[g * 4 + 2].w += xv.w * f.z;
            acc[g * 4 + 3].x += xv.x * f.w; acc[g * 4 + 3].y += xv.y * f.w;
            acc[g * 4 + 3].z += xv.z * f.w; acc[g * 4 + 3].w += xv.w * f.w;
        }
    }
    __half* dst = xh + (size_t)(b_ * 16) * HW + hw;
#pragma unroll
    for (int o = 0; o < 16; o++) {
        uint2 pk;
        pk.x = __builtin_bit_cast(unsigned, __floats2half2_rn(acc[o].x, acc[o].y));
        pk.y = __builtin_bit_cast(unsigned, __floats2half2_rn(acc[o].z, acc[o].w));
        *(uint2*)(dst + (size_t)o * HW) = pk;
    }
}

// ---------------- K2: FUSED dw convs (fp16 packed) + machinery ----------------
// grid (64, 128): x = 32x32 tile (8x8), y = b*16 + c.  512 threads.
__global__ __launch_bounds__(512, 4) void k_fused(const __half* __restrict__ xh,
    const unsigned* __restrict__ wtab,
    const float* __restrict__ bns, const float* __restrict__ bnb,
    __half* __restrict__ y16) {

    const int by  = blockIdx.y;                  // b*16 + c
    const int c   = by & 15;
    const int ty0 = (blockIdx.x >> 3) * 32;      // tile origin (image coords)
    const int tx0 = (blockIdx.x & 7) * 32;
    const int tid = threadIdx.x;

    __shared__ unsigned lxh[52 * 27];                      // fp16 x-tile, rows ty0-10..+41, odd stride
    __shared__ __align__(16) unsigned convt[4 * 46 * 24];  // conv planes, rows ty0-7..+38

    // ---- stage x tile: 52 rows x 26 dwords (52 px), raw u32 copy ----
    {
        const unsigned* xp32 = (const unsigned*)(xh + (size_t)by * HW);
        for (int t = tid; t < 52 * 26; t += 512) {
            int r = t / 26, j = t - r * 26;
            int gy = ty0 - 10 + r, gp = tx0 - 10 + 2 * j;   // gp even; pairs never straddle
            unsigned v = 0;
            if ((unsigned)gy < 256u && (unsigned)gp < 256u)
                v = xp32[(gy << 7) + (gp >> 1)];
            lxh[r * 27 + j] = v;
        }
    }
    __syncthreads();

    // ---- depthwise convs: 46 rows x 23 col-pairs, fp16 packed, alignbit taps ----
    {
        const unsigned* dwc = wtab + 2048 + c * 96;   // block-uniform -> s_load
        for (int u = tid; u < 46 * 23; u += 512) {
            int row = u / 23;
            int d0  = u - row * 23;          // dword offset = pair index
            int pc0 = d0 * 2;                // px offset in 52-wide tile
            h2 acc7 = {0, 0}, acc5 = {0, 0}, acc3 = {0, 0}, acc1 = {0, 0};
#pragma unroll
            for (int a = 0; a < 7; a++) {
                const unsigned* rp = lxh + (row + a) * 27 + d0;
                unsigned q0 = rp[0], q1 = rp[1], q2 = rp[2], q3 = rp[3], q4 = rp[4];
                unsigned p1u = (q0 >> 16) | (q1 << 16);   // v_alignbit_b32
                unsigned p3u = (q1 >> 16) | (q2 << 16);
                unsigned p5u = (q2 >> 16) | (q3 << 16);
                unsigned p7u = (q3 >> 16) | (q4 << 16);
                h2 P[8] = {uh(q0), uh(p1u), uh(q1), uh(p3u),
                           uh(q2), uh(p5u), uh(q3), uh(p7u)};
#pragma unroll
                for (int b = 0; b < 7; b++)
                    acc7 = P[b] * uh(dwc[a * 7 + b]) + acc7;
                if (a >= 1 && a <= 5) {
#pragma unroll
                    for (int b = 0; b < 5; b++)
                        acc5 = P[1 + b] * uh(dwc[49 + (a - 1) * 5 + b]) + acc5;
                }
                if (a >= 2 && a <= 4) {
#pragma unroll
                    for (int b = 0; b < 3; b++)
                        acc3 = P[2 + b] * uh(dwc[74 + (a - 2) * 3 + b]) + acc3;
                }
                if (a == 3)
                    acc1 = P[3] * uh(dwc[83]);
            }
            int iy = ty0 - 7 + row, ix = tx0 - 7 + pc0;
            bool rin = (unsigned)iy < 256u;
            unsigned msk = (rin && (unsigned)ix < 256u ? 0x0000FFFFu : 0u)
                         | (rin && (unsigned)(ix + 1) < 256u ? 0xFFFF0000u : 0u);
            int o = row * 24 + d0;
            convt[o]        = hu(acc1 + uh(dwc[84])) & msk;
            convt[o + 1104] = hu(acc3 + uh(dwc[85])) & msk;
            convt[o + 2208] = hu(acc5 + uh(dwc[86])) & msk;
            convt[o + 3312] = hu(acc7 + uh(dwc[87])) & msk;
        }
    }
    __syncthreads();

    // ---- machinery: one horizontal pixel pair per thread (unchanged) ----
    const int py  = tid >> 4;                    // 0..31
    const int pxp = tid & 15;                    // pair within row

    h2 bh[4];
#pragma unroll
    for (int i = 0; i < 4; i++) {
        const int s = 1 + 2 * i;
        const unsigned* pl = convt + i * 1104;
        const int q    = pxp + (7 - s) / 2;          // start dword within row
        const int topb = (py + 7 - s) * 24 + q;
        const int midb = (py + 7) * 24 + q;
        const int botb = (py + 7 + s) * 24 + q;

        unsigned tt[8], tm[8], tb[8];
#pragma unroll
        for (int k = 0; k <= s; k++) {
            tt[k] = pl[topb + k];
            tm[k] = pl[midb + k];
            tb[k] = pl[botb + k];
        }
        const int m = s >> 1;   // (s-1)/2
        h2 n0  = uh(tt[0]);
        h2 n1  = uh((tt[m] >> 16) | (tt[m + 1] << 16));
        h2 n2  = uh(tt[s]);
        h2 n7  = uh(tm[0]);
        h2 ctr = uh((tm[m] >> 16) | (tm[m + 1] << 16));
        h2 n3  = uh(tm[s]);
        h2 n6  = uh(tb[0]);
        h2 n5  = uh((tb[m] >> 16) | (tb[m + 1] << 16));
        h2 n4  = uh(tb[s]);

        h2 T[8];
        T[0] = ctr - n0; T[1] = ctr - n1; T[2] = ctr - n2; T[3] = ctr - n3;
        T[4] = ctr - n4; T[5] = ctr - n5; T[6] = ctr - n6; T[7] = ctr - n7;
        h2 S[4];
#pragma unroll
        for (int k = 0; k < 4; k++) S[k] = T[k] + T[k + 4];

        const unsigned* wt = wtab + ((c << 2) + i) * 16;   // block-uniform -> s_load
        h2 w10 = uh(wt[0]), w11 = uh(wt[1]), w12 = uh(wt[2]);
        h2 w13x2 = uh(wt[3]), bb1 = uh(wt[4]);

        h2 R[4];
#pragma unroll
        for (int mm = 0; mm < 4; mm++) {
            h2 r = S[(mm + 2) & 3] * w12 + bb1;
            r = S[(mm + 3) & 3] * w11 + r;
            r = S[(mm + 1) & 3] * w10 + r;
            R[mm] = r;
        }
        h2 h8[8];
#pragma unroll
        for (int k = 0; k < 8; k++)
            h8[k] = (T[(k + 4) & 7] * w13x2 + R[k & 3]) * T[k];
        sort8_h2(h8);

        h2 acc = uh(wt[13]);
#pragma unroll
        for (int k = 0; k < 8; k++) acc += h8[k] * uh(wt[5 + k]);
        bh[i] = acc;
    }
    sort4_h2(bh);
    h2 yv = bh[0] * uh(wtab[1024 + (c << 2)]);
#pragma unroll
    for (int k = 1; k < 4; k++) yv = bh[k] * uh(wtab[1024 + (c << 2) + k]) + yv;

    const float bsc = bns[c], bbi = bnb[c];      // block-uniform -> s_load
    float zx = fmaf((float)yv.x, bsc, bbi);
    float zy = fmaf((float)yv.y, bsc, bbi);
    float sx = zx / (1.f + __expf(-zx));
    float sy = zy / (1.f + __expf(-zy));
    *(__half2*)&y16[(size_t)by * HW + (ty0 + py) * 256 + tx0 + 2 * pxp] =
        __floats2half2_rn(sx, sy);
}

// ---------------- K3: final 1x1 16 -> 1 + sigmoid ----------------
__global__ __launch_bounds__(256) void k_final(const __half* __restrict__ y16,
                                               const float* __restrict__ fw,
                                               const float* __restrict__ fb,
                                               float* __restrict__ out) {
    long t  = (long)blockIdx.x * 256 + threadIdx.x;   // pair index
    long p0 = t * 2;
    int  b  = (int)(p0 >> 16);
    int  hw = (int)(p0 & 65535);

    float accx = fb[0], accy = fb[0];
#pragma unroll
    for (int cc = 0; cc < 16; cc++) {
        __half2 h = *(const __half2*)(y16 + (size_t)(b * 16 + cc) * HW + hw);
        float2 v = __half22float2(h);
        float wv = fw[cc];
        accx = fmaf(v.x, wv, accx);
        accy = fmaf(v.y, wv, accy);
    }
    float2 r;
    r.x = 1.f / (1.f + __expf(-accx));
    r.y = 1.f / (1.f + __expf(-accy));
    *(float2*)(out + p0) = r;
}

extern "C" void kernel_launch(void* const* d_in, const int* in_sizes, int n_in,
                              void* d_out, int out_size, void* d_ws, size_t ws_size,
                              hipStream_t stream) {
    (void)in_sizes; (void)n_in; (void)out_size; (void)ws_size;
    const float* cen   = (const float*)d_in[0];
    // d_in[1] = mas (unused by the reference)
    const float* in_w  = (const float*)d_in[2];
    const float* in_b  = (const float*)d_in[3];
    const float* dw_w1 = (const float*)d_in[4];
    const float* dw_b1 = (const float*)d_in[5];
    const float* dw_w3 = (const float*)d_in[6];
    const float* dw_b3 = (const float*)d_in[7];
    const float* dw_w5 = (const float*)d_in[8];
    const float* dw_b5 = (const float*)d_in[9];
    const float* dw_w7 = (const float*)d_in[10];
    const float* dw_b7 = (const float*)d_in[11];
    const float* l1w   = (const float*)d_in[12];
    const float* l1b   = (const float*)d_in[13];
    const float* l2w   = (const float*)d_in[14];
    const float* l2b   = (const float*)d_in[15];
    const float* bw    = (const float*)d_in[16];
    const float* bns   = (const float*)d_in[17];
    const float* bnb   = (const float*)d_in[18];
    const float* fw    = (const float*)d_in[19];
    const float* fb    = (const float*)d_in[20];

    // workspace: xh (16.78 MB) | wtab (16 KB) | y16 (16.78 MB)
    __half*   xh   = (__half*)d_ws;
    unsigned* wtab = (unsigned*)((char*)d_ws + (size_t)16777216);
    __half*   y16  = (__half*)((char*)d_ws + (size_t)16777216 + 16384);
    float*    out  = (float*)d_out;

    k_pack<<<1, 256, 0, stream>>>(l1w, l1b, l2w, l2b, bw,
                                  dw_w1, dw_b1, dw_w3, dw_b3,
                                  dw_w5, dw_b5, dw_w7, dw_b7, wtab);
    k_inconv<<<512, 256, 0, stream>>>(cen, in_w, in_b, xh);
    k_fused<<<dim3(64, 128), 512, 0, stream>>>(xh, wtab, bns, bnb, y16);
    k_final<<<1024, 256, 0, stream>>>(y16, fw, fb, out);
}

// Round 6
// 344.659 us; speedup vs baseline: 1.0889x; 1.0418x over previous
//
#include <hip/hip_runtime.h>
#include <hip/hip_fp16.h>
#include <math.h>

#define HW 65536               // 256*256

typedef float v2f __attribute__((ext_vector_type(2), aligned(8)));
typedef _Float16 h2 __attribute__((ext_vector_type(2)));

__device__ __forceinline__ h2 uh(unsigned u) { return __builtin_bit_cast(h2, u); }
__device__ __forceinline__ unsigned hu(h2 v) { return __builtin_bit_cast(unsigned, v); }

#define CEH(a, b) { h2 _t = __builtin_elementwise_min(a, b); \
                    b = __builtin_elementwise_max(a, b); a = _t; }

__device__ __forceinline__ void sort8_h2(h2* v) {
    CEH(v[0], v[1]); CEH(v[2], v[3]); CEH(v[4], v[5]); CEH(v[6], v[7]);
    CEH(v[0], v[2]); CEH(v[1], v[3]); CEH(v[4], v[6]); CEH(v[5], v[7]);
    CEH(v[1], v[2]); CEH(v[5], v[6]); CEH(v[0], v[4]); CEH(v[3], v[7]);
    CEH(v[1], v[5]); CEH(v[2], v[6]);
    CEH(v[1], v[4]); CEH(v[3], v[6]);
    CEH(v[2], v[4]); CEH(v[3], v[5]);
    CEH(v[3], v[4]);
}
__device__ __forceinline__ void sort4_h2(h2* v) {
    CEH(v[0], v[1]); CEH(v[2], v[3]); CEH(v[0], v[2]); CEH(v[1], v[3]); CEH(v[1], v[2]);
}

// ---------------- K0: pack weights as fp16 {w,w} u32 pairs ----------------
// [0..1023]   machinery per-(c,i): j0..2=l1w, j3=2*l1w[3], j4=l1b, j5..12=l2w, j13=l2b
// [1024..1087] bw
// [2048+c*96 ..]: j0..48=w7, 49..73=w5, 74..82=w3, 83=w1, 84..87=B1,B3,B5,B7
__global__ __launch_bounds__(256) void k_pack(const float* __restrict__ l1w,
                                              const float* __restrict__ l1b,
                                              const float* __restrict__ l2w,
                                              const float* __restrict__ l2b,
                                              const float* __restrict__ bw,
                                              const float* __restrict__ dw_w1,
                                              const float* __restrict__ dw_b1,
                                              const float* __restrict__ dw_w3,
                                              const float* __restrict__ dw_b3,
                                              const float* __restrict__ dw_w5,
                                              const float* __restrict__ dw_b5,
                                              const float* __restrict__ dw_w7,
                                              const float* __restrict__ dw_b7,
                                              unsigned* __restrict__ wtab) {
    for (int t = threadIdx.x; t < 3584; t += 256) {
        float v = 0.f;
        if (t < 1024) {
            int c = t >> 6, i = (t >> 4) & 3, j = t & 15;
            if (j < 3)        v = l1w[i * 64 + c * 4 + j];
            else if (j == 3)  v = 2.f * l1w[i * 64 + c * 4 + 3];
            else if (j == 4)  v = l1b[i * 16 + c];
            else if (j < 13)  v = l2w[i * 128 + c * 8 + (j - 5)];
            else if (j == 13) v = l2b[i * 16 + c];
        } else if (t < 1088) {
            v = bw[t - 1024];
        } else if (t >= 2048) {
            int c = (t - 2048) / 96, j = (t - 2048) - c * 96;
            if (j < 49)       v = dw_w7[c * 49 + j];
            else if (j < 74)  v = dw_w5[c * 25 + (j - 49)];
            else if (j < 83)  v = dw_w3[c * 9 + (j - 74)];
            else if (j == 83) v = dw_w1[c];
            else if (j == 84) v = dw_b1[c];
            else if (j == 85) v = dw_b3[c];
            else if (j == 86) v = dw_b5[c];
            else if (j == 87) v = dw_b7[c];
        }
        unsigned hs = (unsigned)__half_as_ushort(__float2half(v));
        wtab[t] = hs * 0x10001u;
    }
}

// ---------------- K1: in_conv 1x1, 64 -> 16, 2-px float2, LDS weights, fp16 out ----------------
__global__ __launch_bounds__(256, 4) void k_inconv(const float* __restrict__ cen,
                                                   const float* __restrict__ w,
                                                   const float* __restrict__ bias,
                                                   __half* __restrict__ xh) {
    __shared__ float wl[1040];   // wl[i*16+o] = w[o*64+i], + bias at 1024
    int tid = threadIdx.x;
    for (int t = tid; t < 1024; t += 256) wl[t] = w[(t & 15) * 64 + (t >> 4)];
    if (tid < 16) wl[1024 + tid] = bias[tid];
    __syncthreads();

    int pr = blockIdx.x * 256 + tid;      // pair index, 0..262143
    int b_ = pr >> 15;
    int hw = (pr & 32767) * 2;
    const float* src = cen + (size_t)(b_ * 64) * HW + hw;

    v2f acc[16];
#pragma unroll
    for (int o = 0; o < 16; o++) { float bv = wl[1024 + o]; v2f t = {bv, bv}; acc[o] = t; }

#pragma unroll 8
    for (int i = 0; i < 64; i++) {
        v2f xv = *(const v2f*)(src + (size_t)i * HW);
        const float4* wq = (const float4*)&wl[i * 16];   // uniform -> ds broadcast
#pragma unroll
        for (int g = 0; g < 4; g++) {
            float4 f = wq[g];
            acc[g * 4 + 0] += xv * f.x;
            acc[g * 4 + 1] += xv * f.y;
            acc[g * 4 + 2] += xv * f.z;
            acc[g * 4 + 3] += xv * f.w;
        }
    }
    __half* dst = xh + (size_t)(b_ * 16) * HW + hw;
#pragma unroll
    for (int o = 0; o < 16; o++)
        *(__half2*)(dst + (size_t)o * HW) = __floats2half2_rn(acc[o].x, acc[o].y);
}

// ---------------- K2: FUSED dw convs (fp16 packed) + machinery, 64x64 tiles ----------------
// grid (16, 128): x = 64x64 tile (4x4), y = b*16 + c.  1024 threads.
#define LXS 43     // lxh stride (dwords); 84 rows x 42 used
#define CTS 40     // convt stride (dwords); 78 rows x 39 used
#define CTP (78 * CTS)   // convt plane stride = 3120 dwords
__global__ __launch_bounds__(1024, 4) void k_fused(const __half* __restrict__ xh,
    const unsigned* __restrict__ wtab,
    const float* __restrict__ bns, const float* __restrict__ bnb,
    __half* __restrict__ y16) {

    const int by  = blockIdx.y;                  // b*16 + c
    const int c   = by & 15;
    const int ty0 = (blockIdx.x >> 2) * 64;      // tile origin (image coords)
    const int tx0 = (blockIdx.x & 3) * 64;
    const int tid = threadIdx.x;

    __shared__ unsigned lxh[84 * LXS];           // fp16 x-tile, rows ty0-10..+73
    __shared__ unsigned convt[4 * CTP];          // conv planes, rows ty0-7..+70

    // ---- stage x tile: 84 rows x 42 dwords (84 px), raw u32 copy ----
    {
        const unsigned* xp32 = (const unsigned*)(xh + (size_t)by * HW);
        for (int t = tid; t < 84 * 42; t += 1024) {
            int r = t / 42, j = t - r * 42;
            int gy = ty0 - 10 + r, gp = tx0 - 10 + 2 * j;   // gp even; pairs never straddle
            unsigned v = 0;
            if ((unsigned)gy < 256u && (unsigned)gp < 256u)
                v = xp32[(gy << 7) + (gp >> 1)];
            lxh[r * LXS + j] = v;
        }
    }
    __syncthreads();

    // ---- depthwise convs: 78 rows x 39 col-pairs, fp16 packed, alignbit taps ----
    {
        const unsigned* dwc = wtab + 2048 + c * 96;   // block-uniform -> s_load
        for (int u = tid; u < 78 * 39; u += 1024) {
            int row = u / 39;
            int d0  = u - row * 39;          // dword offset = pair index
            h2 acc7 = {0, 0}, acc5 = {0, 0}, acc3 = {0, 0}, acc1 = {0, 0};
#pragma unroll
            for (int a = 0; a < 7; a++) {
                const unsigned* rp = lxh + (row + a) * LXS + d0;
                unsigned q0 = rp[0], q1 = rp[1], q2 = rp[2], q3 = rp[3];
                unsigned p1u = (q0 >> 16) | (q1 << 16);   // v_alignbit_b32
                unsigned p3u = (q1 >> 16) | (q2 << 16);
                unsigned p5u = (q2 >> 16) | (q3 << 16);
                h2 P[7] = {uh(q0), uh(p1u), uh(q1), uh(p3u),
                           uh(q2), uh(p5u), uh(q3)};
#pragma unroll
                for (int b = 0; b < 7; b++)
                    acc7 = P[b] * uh(dwc[a * 7 + b]) + acc7;
                if (a >= 1 && a <= 5) {
#pragma unroll
                    for (int b = 0; b < 5; b++)
                        acc5 = P[1 + b] * uh(dwc[49 + (a - 1) * 5 + b]) + acc5;
                }
                if (a >= 2 && a <= 4) {
#pragma unroll
                    for (int b = 0; b < 3; b++)
                        acc3 = P[2 + b] * uh(dwc[74 + (a - 2) * 3 + b]) + acc3;
                }
                if (a == 3)
                    acc1 = P[3] * uh(dwc[83]);
            }
            int iy = ty0 - 7 + row, ix = tx0 - 7 + 2 * d0;
            bool rin = (unsigned)iy < 256u;
            unsigned msk = (rin && (unsigned)ix < 256u ? 0x0000FFFFu : 0u)
                         | (rin && (unsigned)(ix + 1) < 256u ? 0xFFFF0000u : 0u);
            int o = row * CTS + d0;
            convt[o]           = hu(acc1 + uh(dwc[84])) & msk;
            convt[o + CTP]     = hu(acc3 + uh(dwc[85])) & msk;
            convt[o + 2 * CTP] = hu(acc5 + uh(dwc[86])) & msk;
            convt[o + 3 * CTP] = hu(acc7 + uh(dwc[87])) & msk;
        }
    }
    __syncthreads();

    // ---- machinery: two pixel pairs per thread (rows py, py+32) ----
    const int py  = tid >> 5;                    // 0..31
    const int pxp = tid & 31;                    // pair col within 64-wide tile

#pragma unroll
    for (int rr = 0; rr < 2; rr++) {
        const int R = py + (rr << 5);            // output row within tile, 0..63

        h2 bh[4];
#pragma unroll
        for (int i = 0; i < 4; i++) {
            const int s = 1 + 2 * i;
            const unsigned* pl = convt + i * CTP;
            const int q    = pxp + (7 - s) / 2;      // start dword within row
            const int topb = (R + 7 - s) * CTS + q;
            const int midb = (R + 7) * CTS + q;
            const int botb = (R + 7 + s) * CTS + q;

            unsigned tt[8], tm[8], tb[8];
#pragma unroll
            for (int k = 0; k <= s; k++) {
                tt[k] = pl[topb + k];
                tm[k] = pl[midb + k];
                tb[k] = pl[botb + k];
            }
            const int m = s >> 1;   // (s-1)/2
            h2 n0  = uh(tt[0]);
            h2 n1  = uh((tt[m] >> 16) | (tt[m + 1] << 16));
            h2 n2  = uh(tt[s]);
            h2 n7  = uh(tm[0]);
            h2 ctr = uh((tm[m] >> 16) | (tm[m + 1] << 16));
            h2 n3  = uh(tm[s]);
            h2 n6  = uh(tb[0]);
            h2 n5  = uh((tb[m] >> 16) | (tb[m + 1] << 16));
            h2 n4  = uh(tb[s]);

            h2 T[8];
            T[0] = ctr - n0; T[1] = ctr - n1; T[2] = ctr - n2; T[3] = ctr - n3;
            T[4] = ctr - n4; T[5] = ctr - n5; T[6] = ctr - n6; T[7] = ctr - n7;
            h2 S[4];
#pragma unroll
            for (int k = 0; k < 4; k++) S[k] = T[k] + T[k + 4];

            const unsigned* wt = wtab + ((c << 2) + i) * 16;   // block-uniform -> s_load
            h2 w10 = uh(wt[0]), w11 = uh(wt[1]), w12 = uh(wt[2]);
            h2 w13x2 = uh(wt[3]), bb1 = uh(wt[4]);

            h2 R4[4];
#pragma unroll
            for (int mm = 0; mm < 4; mm++) {
                h2 r = S[(mm + 2) & 3] * w12 + bb1;
                r = S[(mm + 3) & 3] * w11 + r;
                r = S[(mm + 1) & 3] * w10 + r;
                R4[mm] = r;
            }
            h2 h8[8];
#pragma unroll
            for (int k = 0; k < 8; k++)
                h8[k] = (T[(k + 4) & 7] * w13x2 + R4[k & 3]) * T[k];
            sort8_h2(h8);

            h2 acc = uh(wt[13]);
#pragma unroll
            for (int k = 0; k < 8; k++) acc += h8[k] * uh(wt[5 + k]);
            bh[i] = acc;
        }
        sort4_h2(bh);
        h2 yv = bh[0] * uh(wtab[1024 + (c << 2)]);
#pragma unroll
        for (int k = 1; k < 4; k++) yv = bh[k] * uh(wtab[1024 + (c << 2) + k]) + yv;

        const float bsc = bns[c], bbi = bnb[c];  // block-uniform -> s_load
        float zx = fmaf((float)yv.x, bsc, bbi);
        float zy = fmaf((float)yv.y, bsc, bbi);
        float sx = zx / (1.f + __expf(-zx));
        float sy = zy / (1.f + __expf(-zy));
        *(__half2*)&y16[(size_t)by * HW + (ty0 + R) * 256 + tx0 + 2 * pxp] =
            __floats2half2_rn(sx, sy);
    }
}

// ---------------- K3: final 1x1 16 -> 1 + sigmoid ----------------
__global__ __launch_bounds__(256) void k_final(const __half* __restrict__ y16,
                                               const float* __restrict__ fw,
                                               const float* __restrict__ fb,
                                               float* __restrict__ out) {
    long t  = (long)blockIdx.x * 256 + threadIdx.x;   // pair index
    long p0 = t * 2;
    int  b  = (int)(p0 >> 16);
    int  hw = (int)(p0 & 65535);

    float accx = fb[0], accy = fb[0];
#pragma unroll
    for (int cc = 0; cc < 16; cc++) {
        __half2 h = *(const __half2*)(y16 + (size_t)(b * 16 + cc) * HW + hw);
        float2 v = __half22float2(h);
        float wv = fw[cc];
        accx = fmaf(v.x, wv, accx);
        accy = fmaf(v.y, wv, accy);
    }
    float2 r;
    r.x = 1.f / (1.f + __expf(-accx));
    r.y = 1.f / (1.f + __expf(-accy));
    *(float2*)(out + p0) = r;
}

extern "C" void kernel_launch(void* const* d_in, const int* in_sizes, int n_in,
                              void* d_out, int out_size, void* d_ws, size_t ws_size,
                              hipStream_t stream) {
    (void)in_sizes; (void)n_in; (void)out_size; (void)ws_size;
    const float* cen   = (const float*)d_in[0];
    // d_in[1] = mas (unused by the reference)
    const float* in_w  = (const float*)d_in[2];
    const float* in_b  = (const float*)d_in[3];
    const float* dw_w1 = (const float*)d_in[4];
    const float* dw_b1 = (const float*)d_in[5];
    const float* dw_w3 = (const float*)d_in[6];
    const float* dw_b3 = (const float*)d_in[7];
    const float* dw_w5 = (const float*)d_in[8];
    const float* dw_b5 = (const float*)d_in[9];
    const float* dw_w7 = (const float*)d_in[10];
    const float* dw_b7 = (const float*)d_in[11];
    const float* l1w   = (const float*)d_in[12];
    const float* l1b   = (const float*)d_in[13];
    const float* l2w   = (const float*)d_in[14];
    const float* l2b   = (const float*)d_in[15];
    const float* bw    = (const float*)d_in[16];
    const float* bns   = (const float*)d_in[17];
    const float* bnb   = (const float*)d_in[18];
    const float* fw    = (const float*)d_in[19];
    const float* fb    = (const float*)d_in[20];

    // workspace: xh (16.78 MB) | wtab (16 KB) | y16 (16.78 MB)
    __half*   xh   = (__half*)d_ws;
    unsigned* wtab = (unsigned*)((char*)d_ws + (size_t)16777216);
    __half*   y16  = (__half*)((char*)d_ws + (size_t)16777216 + 16384);
    float*    out  = (float*)d_out;

    k_pack<<<1, 256, 0, stream>>>(l1w, l1b, l2w, l2b, bw,
                                  dw_w1, dw_b1, dw_w3, dw_b3,
                                  dw_w5, dw_b5, dw_w7, dw_b7, wtab);
    k_inconv<<<1024, 256, 0, stream>>>(cen, in_w, in_b, xh);
    k_fused<<<dim3(16, 128), 1024, 0, stream>>>(xh, wtab, bns, bnb, y16);
    k_final<<<1024, 256, 0, stream>>>(y16, fw, fb, out);
}

// Round 7
// 333.098 us; speedup vs baseline: 1.1267x; 1.0347x over previous
//
#include <hip/hip_runtime.h>
#include <hip/hip_fp16.h>
#include <math.h>

#define HW 65536               // 256*256

typedef float v2f __attribute__((ext_vector_type(2), aligned(8)));
typedef _Float16 h2 __attribute__((ext_vector_type(2)));

__device__ __forceinline__ h2 uh(unsigned u) { return __builtin_bit_cast(h2, u); }
__device__ __forceinline__ unsigned hu(h2 v) { return __builtin_bit_cast(unsigned, v); }
__device__ __forceinline__ unsigned algn(unsigned lo, unsigned hi) {
    return (lo >> 16) | (hi << 16);          // v_alignbit_b32
}

#define CEH(a, b) { h2 _t = __builtin_elementwise_min(a, b); \
                    b = __builtin_elementwise_max(a, b); a = _t; }

__device__ __forceinline__ void sort8_h2(h2* v) {
    CEH(v[0], v[1]); CEH(v[2], v[3]); CEH(v[4], v[5]); CEH(v[6], v[7]);
    CEH(v[0], v[2]); CEH(v[1], v[3]); CEH(v[4], v[6]); CEH(v[5], v[7]);
    CEH(v[1], v[2]); CEH(v[5], v[6]); CEH(v[0], v[4]); CEH(v[3], v[7]);
    CEH(v[1], v[5]); CEH(v[2], v[6]);
    CEH(v[1], v[4]); CEH(v[3], v[6]);
    CEH(v[2], v[4]); CEH(v[3], v[5]);
    CEH(v[3], v[4]);
}
__device__ __forceinline__ void sort4_h2(h2* v) {
    CEH(v[0], v[1]); CEH(v[2], v[3]); CEH(v[0], v[2]); CEH(v[1], v[3]); CEH(v[1], v[2]);
}

// ---------------- K0: pack weights as fp16 {w,w} u32 pairs (unchanged) ----------------
__global__ __launch_bounds__(256) void k_pack(const float* __restrict__ l1w,
                                              const float* __restrict__ l1b,
                                              const float* __restrict__ l2w,
                                              const float* __restrict__ l2b,
                                              const float* __restrict__ bw,
                                              const float* __restrict__ dw_w1,
                                              const float* __restrict__ dw_b1,
                                              const float* __restrict__ dw_w3,
                                              const float* __restrict__ dw_b3,
                                              const float* __restrict__ dw_w5,
                                              const float* __restrict__ dw_b5,
                                              const float* __restrict__ dw_w7,
                                              const float* __restrict__ dw_b7,
                                              unsigned* __restrict__ wtab) {
    for (int t = threadIdx.x; t < 3584; t += 256) {
        float v = 0.f;
        if (t < 1024) {
            int c = t >> 6, i = (t >> 4) & 3, j = t & 15;
            if (j < 3)        v = l1w[i * 64 + c * 4 + j];
            else if (j == 3)  v = 2.f * l1w[i * 64 + c * 4 + 3];
            else if (j == 4)  v = l1b[i * 16 + c];
            else if (j < 13)  v = l2w[i * 128 + c * 8 + (j - 5)];
            else if (j == 13) v = l2b[i * 16 + c];
        } else if (t < 1088) {
            v = bw[t - 1024];
        } else if (t >= 2048) {
            int c = (t - 2048) / 96, j = (t - 2048) - c * 96;
            if (j < 49)       v = dw_w7[c * 49 + j];
            else if (j < 74)  v = dw_w5[c * 25 + (j - 49)];
            else if (j < 83)  v = dw_w3[c * 9 + (j - 74)];
            else if (j == 83) v = dw_w1[c];
            else if (j == 84) v = dw_b1[c];
            else if (j == 85) v = dw_b3[c];
            else if (j == 86) v = dw_b5[c];
            else if (j == 87) v = dw_b7[c];
        }
        unsigned hs = (unsigned)__half_as_ushort(__float2half(v));
        wtab[t] = hs * 0x10001u;
    }
}

// ---------------- K1: in_conv (unchanged from R6) ----------------
__global__ __launch_bounds__(256, 4) void k_inconv(const float* __restrict__ cen,
                                                   const float* __restrict__ w,
                                                   const float* __restrict__ bias,
                                                   __half* __restrict__ xh) {
    __shared__ float wl[1040];
    int tid = threadIdx.x;
    for (int t = tid; t < 1024; t += 256) wl[t] = w[(t & 15) * 64 + (t >> 4)];
    if (tid < 16) wl[1024 + tid] = bias[tid];
    __syncthreads();

    int pr = blockIdx.x * 256 + tid;
    int b_ = pr >> 15;
    int hw = (pr & 32767) * 2;
    const float* src = cen + (size_t)(b_ * 64) * HW + hw;

    v2f acc[16];
#pragma unroll
    for (int o = 0; o < 16; o++) { float bv = wl[1024 + o]; v2f t = {bv, bv}; acc[o] = t; }

#pragma unroll 8
    for (int i = 0; i < 64; i++) {
        v2f xv = *(const v2f*)(src + (size_t)i * HW);
        const float4* wq = (const float4*)&wl[i * 16];
#pragma unroll
        for (int g = 0; g < 4; g++) {
            float4 f = wq[g];
            acc[g * 4 + 0] += xv * f.x;
            acc[g * 4 + 1] += xv * f.y;
            acc[g * 4 + 2] += xv * f.z;
            acc[g * 4 + 3] += xv * f.w;
        }
    }
    __half* dst = xh + (size_t)(b_ * 16) * HW + hw;
#pragma unroll
    for (int o = 0; o < 16; o++)
        *(__half2*)(dst + (size_t)o * HW) = __floats2half2_rn(acc[o].x, acc[o].y);
}

// ---------------- K2: FUSED, b64-aligned LDS layout ----------------
// 64x64 tile, 1024 threads.  Planes stored with per-plane column origin:
//   plane i origin px = -(7 + 2*pad_i), pad_i = 1 for s in {1,5}, 0 for s in {3,7}
// so every machinery span start D = 2g + (7-s)/2 + pad_i is EVEN -> ds_read_b64.
#define LXS 44           // lxh dwords/row (even: b64-aligned rows), 42 used
#define CTS 42           // convt dwords/row (even), 40/41 used
#define CTP (78 * CTS)   // convt plane stride

template<int S, int PAD>
__device__ __forceinline__ void branch_pair(const unsigned* pl, int R, int g,
                                            const unsigned* wt, h2* outA, h2* outB) {
    const int D = 2 * g + (7 - S) / 2 + PAD;     // even
    const int L = (S + 3) / 2;                   // b64 count per span (>= (S+2)/2 dwords)
    const unsigned* pt = pl + (R + 7 - S) * CTS + D;
    const unsigned* pm = pl + (R + 7) * CTS + D;
    const unsigned* pb = pl + (R + 7 + S) * CTS + D;
    unsigned ut[2 * L], um[2 * L], ub[2 * L];
#pragma unroll
    for (int k = 0; k < L; k++) {
        *(uint2*)&ut[2 * k] = *(const uint2*)(pt + 2 * k);   // ds_read_b64
        *(uint2*)&um[2 * k] = *(const uint2*)(pm + 2 * k);
        *(uint2*)&ub[2 * k] = *(const uint2*)(pb + 2 * k);
    }
#pragma unroll
    for (int dw = 0; dw < 2; dw++) {             // pair A (px 4g,4g+1), pair B (+2,+3)
        h2 n0 = uh(ut[dw]);
        h2 n1 = uh(algn(ut[(S - 1) / 2 + dw], ut[(S + 1) / 2 + dw]));
        h2 n2 = uh(ut[S + dw]);
        h2 n7 = uh(um[dw]);
        h2 ct = uh(algn(um[(S - 1) / 2 + dw], um[(S + 1) / 2 + dw]));
        h2 n3 = uh(um[S + dw]);
        h2 n6 = uh(ub[dw]);
        h2 n5 = uh(algn(ub[(S - 1) / 2 + dw], ub[(S + 1) / 2 + dw]));
        h2 n4 = uh(ub[S + dw]);

        h2 T[8];
        T[0] = ct - n0; T[1] = ct - n1; T[2] = ct - n2; T[3] = ct - n3;
        T[4] = ct - n4; T[5] = ct - n5; T[6] = ct - n6; T[7] = ct - n7;
        h2 Sm[4];
#pragma unroll
        for (int k = 0; k < 4; k++) Sm[k] = T[k] + T[k + 4];

        h2 w10 = uh(wt[0]), w11 = uh(wt[1]), w12 = uh(wt[2]);
        h2 w13x2 = uh(wt[3]), bb1 = uh(wt[4]);

        h2 R4[4];
#pragma unroll
        for (int mm = 0; mm < 4; mm++) {
            h2 r = Sm[(mm + 2) & 3] * w12 + bb1;
            r = Sm[(mm + 3) & 3] * w11 + r;
            r = Sm[(mm + 1) & 3] * w10 + r;
            R4[mm] = r;
        }
        h2 h8[8];
#pragma unroll
        for (int k = 0; k < 8; k++)
            h8[k] = (T[(k + 4) & 7] * w13x2 + R4[k & 3]) * T[k];
        sort8_h2(h8);

        h2 acc = uh(wt[13]);
#pragma unroll
        for (int k = 0; k < 8; k++) acc += h8[k] * uh(wt[5 + k]);
        if (dw == 0) *outA = acc; else *outB = acc;
    }
}

__device__ __forceinline__ unsigned tail_px(h2* bh, const unsigned* __restrict__ wtab,
                                            int c, float bsc, float bbi) {
    sort4_h2(bh);
    h2 yv = bh[0] * uh(wtab[1024 + (c << 2)]);
#pragma unroll
    for (int k = 1; k < 4; k++) yv = bh[k] * uh(wtab[1024 + (c << 2) + k]) + yv;
    float zx = fmaf((float)yv.x, bsc, bbi);
    float zy = fmaf((float)yv.y, bsc, bbi);
    float sx = zx / (1.f + __expf(-zx));
    float sy = zy / (1.f + __expf(-zy));
    return __builtin_bit_cast(unsigned, __floats2half2_rn(sx, sy));
}

__global__ __launch_bounds__(1024, 8) void k_fused(const __half* __restrict__ xh,
    const unsigned* __restrict__ wtab,
    const float* __restrict__ bns, const float* __restrict__ bnb,
    __half* __restrict__ y16) {

    const int by  = blockIdx.y;                  // b*16 + c
    const int c   = by & 15;
    const int ty0 = (blockIdx.x >> 2) * 64;
    const int tx0 = (blockIdx.x & 3) * 64;
    const int tid = threadIdx.x;

    __shared__ unsigned lxh[84 * LXS];           // fp16 x-tile, rows ty0-10..+73
    __shared__ unsigned convt[4 * CTP];          // conv planes, rows ty0-7..+70

    // ---- stage: 84 rows x 21 uint2 (b64 LDS writes) ----
    {
        const unsigned* xp32 = (const unsigned*)(xh + (size_t)by * HW);
        for (int t = tid; t < 84 * 21; t += 1024) {
            int r = t / 21, j = t - r * 21;
            int gy = ty0 - 10 + r;
            int gp = tx0 - 10 + 4 * j;           // even px
            unsigned v0 = 0, v1 = 0;
            if ((unsigned)gy < 256u) {
                const unsigned* rp = xp32 + (gy << 7);
                if ((unsigned)gp < 256u)       v0 = rp[gp >> 1];
                if ((unsigned)(gp + 2) < 256u) v1 = rp[(gp >> 1) + 1];
            }
            uint2 st = {v0, v1};
            *(uint2*)&lxh[r * LXS + 2 * j] = st;
        }
    }
    __syncthreads();

    // ---- depthwise convs: 78 rows x 20 4-px groups, b64 reads, taps shared ----
    {
        const unsigned* dwc = wtab + 2048 + c * 96;   // block-uniform
        for (int u = tid; u < 78 * 20; u += 1024) {
            int row = u / 20;
            int g   = u - row * 20;              // output px p0 = 4g-7 (pairs d0=2g,2g+1)
            h2 a7A = {0, 0}, a7B = {0, 0}, a5A = {0, 0}, a5B = {0, 0};
            h2 a3A = {0, 0}, a3B = {0, 0}, a1A = {0, 0}, a1B = {0, 0};
#pragma unroll
            for (int a = 0; a < 7; a++) {
                const unsigned* rp = lxh + (row + a) * LXS + 2 * g;
                uint2 w0 = *(const uint2*)rp;         // dwords 0,1  (b64)
                uint2 w1 = *(const uint2*)(rp + 2);   // 2,3
                uint2 w2 = *(const uint2*)(rp + 4);   // 4,(5 unused)
                unsigned u0 = w0.x, u1 = w0.y, u2 = w1.x, u3 = w1.y, u4 = w2.x;
                h2 E[9] = {uh(u0), uh(algn(u0, u1)), uh(u1), uh(algn(u1, u2)),
                           uh(u2), uh(algn(u2, u3)), uh(u3), uh(algn(u3, u4)), uh(u4)};
#pragma unroll
                for (int b = 0; b < 7; b++) {
                    h2 wv = uh(dwc[a * 7 + b]);
                    a7A = E[b] * wv + a7A;  a7B = E[b + 2] * wv + a7B;
                }
                if (a >= 1 && a <= 5) {
#pragma unroll
                    for (int b = 0; b < 5; b++) {
                        h2 wv = uh(dwc[49 + (a - 1) * 5 + b]);
                        a5A = E[b + 1] * wv + a5A;  a5B = E[b + 3] * wv + a5B;
                    }
                }
                if (a >= 2 && a <= 4) {
#pragma unroll
                    for (int b = 0; b < 3; b++) {
                        h2 wv = uh(dwc[74 + (a - 2) * 3 + b]);
                        a3A = E[b + 2] * wv + a3A;  a3B = E[b + 4] * wv + a3B;
                    }
                }
                if (a == 3) {
                    h2 wv = uh(dwc[83]);
                    a1A = E[3] * wv;  a1B = E[5] * wv;
                }
            }
            int iy = ty0 - 7 + row;
            bool rin = (unsigned)iy < 256u;
            int ix0 = tx0 - 7 + 4 * g;
            unsigned mA = (rin && (unsigned)ix0 < 256u ? 0x0000FFFFu : 0u)
                        | (rin && (unsigned)(ix0 + 1) < 256u ? 0xFFFF0000u : 0u);
            unsigned mB = (rin && (unsigned)(ix0 + 2) < 256u ? 0x0000FFFFu : 0u)
                        | (rin && (unsigned)(ix0 + 3) < 256u ? 0xFFFF0000u : 0u);
            int o = row * CTS + 2 * g;
            uint2 s3 = {hu(a3A + uh(dwc[85])) & mA, hu(a3B + uh(dwc[85])) & mB};
            uint2 s7 = {hu(a7A + uh(dwc[87])) & mA, hu(a7B + uh(dwc[87])) & mB};
            *(uint2*)&convt[CTP + o]     = s3;        // pad 0 -> b64
            *(uint2*)&convt[3 * CTP + o] = s7;        // pad 0 -> b64
            convt[o + 1]                 = hu(a1A + uh(dwc[84])) & mA;   // pad 1
            convt[o + 2]                 = hu(a1B + uh(dwc[84])) & mB;
            convt[2 * CTP + o + 1]       = hu(a5A + uh(dwc[86])) & mA;   // pad 1
            convt[2 * CTP + o + 2]       = hu(a5B + uh(dwc[86])) & mB;
        }
    }
    __syncthreads();

    // ---- machinery: one 4-px group per thread, b64 spans ----
    const int R = tid >> 4;                      // 0..63
    const int g = tid & 15;                      // px 4g..4g+3

    h2 bhA[4], bhB[4];
    branch_pair<1, 1>(convt,           R, g, wtab + ((c << 2) + 0) * 16, &bhA[0], &bhB[0]);
    branch_pair<3, 0>(convt + CTP,     R, g, wtab + ((c << 2) + 1) * 16, &bhA[1], &bhB[1]);
    branch_pair<5, 1>(convt + 2 * CTP, R, g, wtab + ((c << 2) + 2) * 16, &bhA[2], &bhB[2]);
    branch_pair<7, 0>(convt + 3 * CTP, R, g, wtab + ((c << 2) + 3) * 16, &bhA[3], &bhB[3]);

    const float bsc = bns[c], bbi = bnb[c];
    unsigned r0 = tail_px(bhA, wtab, c, bsc, bbi);
    unsigned r1 = tail_px(bhB, wtab, c, bsc, bbi);
    uint2 st = {r0, r1};
    *(uint2*)&y16[(size_t)by * HW + (ty0 + R) * 256 + tx0 + 4 * g] = st;
}

// ---------------- K3: final 1x1 16 -> 1 + sigmoid (unchanged) ----------------
__global__ __launch_bounds__(256) void k_final(const __half* __restrict__ y16,
                                               const float* __restrict__ fw,
                                               const float* __restrict__ fb,
                                               float* __restrict__ out) {
    long t  = (long)blockIdx.x * 256 + threadIdx.x;
    long p0 = t * 2;
    int  b  = (int)(p0 >> 16);
    int  hw = (int)(p0 & 65535);

    float accx = fb[0], accy = fb[0];
#pragma unroll
    for (int cc = 0; cc < 16; cc++) {
        __half2 h = *(const __half2*)(y16 + (size_t)(b * 16 + cc) * HW + hw);
        float2 v = __half22float2(h);
        float wv = fw[cc];
        accx = fmaf(v.x, wv, accx);
        accy = fmaf(v.y, wv, accy);
    }
    float2 r;
    r.x = 1.f / (1.f + __expf(-accx));
    r.y = 1.f / (1.f + __expf(-accy));
    *(float2*)(out + p0) = r;
}

extern "C" void kernel_launch(void* const* d_in, const int* in_sizes, int n_in,
                              void* d_out, int out_size, void* d_ws, size_t ws_size,
                              hipStream_t stream) {
    (void)in_sizes; (void)n_in; (void)out_size; (void)ws_size;
    const float* cen   = (const float*)d_in[0];
    // d_in[1] = mas (unused by the reference)
    const float* in_w  = (const float*)d_in[2];
    const float* in_b  = (const float*)d_in[3];
    const float* dw_w1 = (const float*)d_in[4];
    const float* dw_b1 = (const float*)d_in[5];
    const float* dw_w3 = (const float*)d_in[6];
    const float* dw_b3 = (const float*)d_in[7];
    const float* dw_w5 = (const float*)d_in[8];
    const float* dw_b5 = (const float*)d_in[9];
    const float* dw_w7 = (const float*)d_in[10];
    const float* dw_b7 = (const float*)d_in[11];
    const float* l1w   = (const float*)d_in[12];
    const float* l1b   = (const float*)d_in[13];
    const float* l2w   = (const float*)d_in[14];
    const float* l2b   = (const float*)d_in[15];
    const float* bw    = (const float*)d_in[16];
    const float* bns   = (const float*)d_in[17];
    const float* bnb   = (const float*)d_in[18];
    const float* fw    = (const float*)d_in[19];
    const float* fb    = (const float*)d_in[20];

    // workspace: xh (16.78 MB) | wtab (16 KB) | y16 (16.78 MB)
    __half*   xh   = (__half*)d_ws;
    unsigned* wtab = (unsigned*)((char*)d_ws + (size_t)16777216);
    __half*   y16  = (__half*)((char*)d_ws + (size_t)16777216 + 16384);
    float*    out  = (float*)d_out;

    k_pack<<<1, 256, 0, stream>>>(l1w, l1b, l2w, l2b, bw,
                                  dw_w1, dw_b1, dw_w3, dw_b3,
                                  dw_w5, dw_b5, dw_w7, dw_b7, wtab);
    k_inconv<<<1024, 256, 0, stream>>>(cen, in_w, in_b, xh);
    k_fused<<<dim3(16, 128), 1024, 0, stream>>>(xh, wtab, bns, bnb, y16);
    k_final<<<1024, 256, 0, stream>>>(y16, fw, fb, out);
}

// Round 8
// 332.469 us; speedup vs baseline: 1.1289x; 1.0019x over previous
//
#include <hip/hip_runtime.h>
#include <hip/hip_fp16.h>
#include <math.h>

#define HW 65536               // 256*256

typedef float v2f __attribute__((ext_vector_type(2), aligned(8)));
typedef _Float16 h2 __attribute__((ext_vector_type(2)));

__device__ __forceinline__ h2 uh(unsigned u) { return __builtin_bit_cast(h2, u); }
__device__ __forceinline__ unsigned hu(h2 v) { return __builtin_bit_cast(unsigned, v); }
__device__ __forceinline__ unsigned algn(unsigned lo, unsigned hi) {
    return (lo >> 16) | (hi << 16);          // v_alignbit_b32
}

#define CEH(a, b) { h2 _t = __builtin_elementwise_min(a, b); \
                    b = __builtin_elementwise_max(a, b); a = _t; }

__device__ __forceinline__ void sort8_h2(h2* v) {
    CEH(v[0], v[1]); CEH(v[2], v[3]); CEH(v[4], v[5]); CEH(v[6], v[7]);
    CEH(v[0], v[2]); CEH(v[1], v[3]); CEH(v[4], v[6]); CEH(v[5], v[7]);
    CEH(v[1], v[2]); CEH(v[5], v[6]); CEH(v[0], v[4]); CEH(v[3], v[7]);
    CEH(v[1], v[5]); CEH(v[2], v[6]);
    CEH(v[1], v[4]); CEH(v[3], v[6]);
    CEH(v[2], v[4]); CEH(v[3], v[5]);
    CEH(v[3], v[4]);
}
__device__ __forceinline__ void sort4_h2(h2* v) {
    CEH(v[0], v[1]); CEH(v[2], v[3]); CEH(v[0], v[2]); CEH(v[1], v[3]); CEH(v[1], v[2]);
}

// ---------------- K0: pack weights ----------------
// u32 fp16-pair section (wtab):
//   [0..1023] machinery per-(c,i); [1024..1087] bw; [2048+c*96..] dw weights
// float section (wtf = wtab + 4096 dwords):
//   wtf[i*16+o] = in_conv_w[o*64+i]; wtf[1024+o] = in_conv_b[o]
__global__ __launch_bounds__(256) void k_pack(const float* __restrict__ l1w,
                                              const float* __restrict__ l1b,
                                              const float* __restrict__ l2w,
                                              const float* __restrict__ l2b,
                                              const float* __restrict__ bw,
                                              const float* __restrict__ dw_w1,
                                              const float* __restrict__ dw_b1,
                                              const float* __restrict__ dw_w3,
                                              const float* __restrict__ dw_b3,
                                              const float* __restrict__ dw_w5,
                                              const float* __restrict__ dw_b5,
                                              const float* __restrict__ dw_w7,
                                              const float* __restrict__ dw_b7,
                                              const float* __restrict__ in_w,
                                              const float* __restrict__ in_b,
                                              unsigned* __restrict__ wtab) {
    for (int t = threadIdx.x; t < 3584; t += 256) {
        float v = 0.f;
        if (t < 1024) {
            int c = t >> 6, i = (t >> 4) & 3, j = t & 15;
            if (j < 3)        v = l1w[i * 64 + c * 4 + j];
            else if (j == 3)  v = 2.f * l1w[i * 64 + c * 4 + 3];
            else if (j == 4)  v = l1b[i * 16 + c];
            else if (j < 13)  v = l2w[i * 128 + c * 8 + (j - 5)];
            else if (j == 13) v = l2b[i * 16 + c];
        } else if (t < 1088) {
            v = bw[t - 1024];
        } else if (t >= 2048) {
            int c = (t - 2048) / 96, j = (t - 2048) - c * 96;
            if (j < 49)       v = dw_w7[c * 49 + j];
            else if (j < 74)  v = dw_w5[c * 25 + (j - 49)];
            else if (j < 83)  v = dw_w3[c * 9 + (j - 74)];
            else if (j == 83) v = dw_w1[c];
            else if (j == 84) v = dw_b1[c];
            else if (j == 85) v = dw_b3[c];
            else if (j == 86) v = dw_b5[c];
            else if (j == 87) v = dw_b7[c];
        }
        unsigned hs = (unsigned)__half_as_ushort(__float2half(v));
        wtab[t] = hs * 0x10001u;
    }
    float* wtf = (float*)(wtab + 4096);
    for (int t = threadIdx.x; t < 1040; t += 256) {
        wtf[t] = (t < 1024) ? in_w[(t & 15) * 64 + (t >> 4)] : in_b[t - 1024];
    }
}

// ---------------- K1: in_conv 1x1 64->16, SGPR weights, no LDS, no barrier ----------------
__global__ __launch_bounds__(256) void k_inconv(const float* __restrict__ cen,
                                                const float* __restrict__ wtf,
                                                __half* __restrict__ xh) {
    int pr = blockIdx.x * 256 + threadIdx.x;     // pair index, 0..262143
    int b_ = pr >> 15;
    int hw = (pr & 32767) * 2;
    const float* src = cen + (size_t)(b_ * 64) * HW + hw;

    v2f acc[16];
#pragma unroll
    for (int o = 0; o < 16; o++) { float bv = wtf[1024 + o]; v2f t = {bv, bv}; acc[o] = t; }

#pragma unroll 8
    for (int i = 0; i < 64; i++) {
        v2f xv = *(const v2f*)(src + (size_t)i * HW);
#pragma unroll
        for (int o = 0; o < 16; o++)
            acc[o] += xv * wtf[i * 16 + o];      // uniform -> s_load, SGPR operand
    }
    __half* dst = xh + (size_t)(b_ * 16) * HW + hw;
#pragma unroll
    for (int o = 0; o < 16; o++)
        *(__half2*)(dst + (size_t)o * HW) = __floats2half2_rn(acc[o].x, acc[o].y);
}

// ---------------- K2: FUSED, b64-aligned LDS layout (R7 + loop trims) ----------------
#define LXS 44           // lxh dwords/row (even: b64-aligned rows), 42 used
#define CTS 42           // convt dwords/row (even), 40/41 used
#define CTP (78 * CTS)   // convt plane stride

template<int S, int PAD>
__device__ __forceinline__ void branch_pair(const unsigned* pl, int R, int g,
                                            const unsigned* wt, h2* outA, h2* outB) {
    const int D = 2 * g + (7 - S) / 2 + PAD;     // even
    const int L = (S + 3) / 2;                   // b64 count per span
    const unsigned* pt = pl + (R + 7 - S) * CTS + D;
    const unsigned* pm = pl + (R + 7) * CTS + D;
    const unsigned* pb = pl + (R + 7 + S) * CTS + D;
    unsigned ut[2 * L], um[2 * L], ub[2 * L];
#pragma unroll
    for (int k = 0; k < L; k++) {
        *(uint2*)&ut[2 * k] = *(const uint2*)(pt + 2 * k);   // ds_read_b64
        *(uint2*)&um[2 * k] = *(const uint2*)(pm + 2 * k);
        *(uint2*)&ub[2 * k] = *(const uint2*)(pb + 2 * k);
    }
#pragma unroll
    for (int dw = 0; dw < 2; dw++) {             // pair A (px 4g,4g+1), pair B (+2,+3)
        h2 n0 = uh(ut[dw]);
        h2 n1 = uh(algn(ut[(S - 1) / 2 + dw], ut[(S + 1) / 2 + dw]));
        h2 n2 = uh(ut[S + dw]);
        h2 n7 = uh(um[dw]);
        h2 ct = uh(algn(um[(S - 1) / 2 + dw], um[(S + 1) / 2 + dw]));
        h2 n3 = uh(um[S + dw]);
        h2 n6 = uh(ub[dw]);
        h2 n5 = uh(algn(ub[(S - 1) / 2 + dw], ub[(S + 1) / 2 + dw]));
        h2 n4 = uh(ub[S + dw]);

        h2 T[8];
        T[0] = ct - n0; T[1] = ct - n1; T[2] = ct - n2; T[3] = ct - n3;
        T[4] = ct - n4; T[5] = ct - n5; T[6] = ct - n6; T[7] = ct - n7;
        h2 Sm[4];
#pragma unroll
        for (int k = 0; k < 4; k++) Sm[k] = T[k] + T[k + 4];

        h2 w10 = uh(wt[0]), w11 = uh(wt[1]), w12 = uh(wt[2]);
        h2 w13x2 = uh(wt[3]), bb1 = uh(wt[4]);

        h2 R4[4];
#pragma unroll
        for (int mm = 0; mm < 4; mm++) {
            h2 r = Sm[(mm + 2) & 3] * w12 + bb1;
            r = Sm[(mm + 3) & 3] * w11 + r;
            r = Sm[(mm + 1) & 3] * w10 + r;
            R4[mm] = r;
        }
        h2 h8[8];
#pragma unroll
        for (int k = 0; k < 8; k++)
            h8[k] = (T[(k + 4) & 7] * w13x2 + R4[k & 3]) * T[k];
        sort8_h2(h8);

        h2 acc = uh(wt[13]);
#pragma unroll
        for (int k = 0; k < 8; k++) acc += h8[k] * uh(wt[5 + k]);
        if (dw == 0) *outA = acc; else *outB = acc;
    }
}

__device__ __forceinline__ unsigned tail_px(h2* bh, const unsigned* __restrict__ wtab,
                                            int c, float bsc, float bbi) {
    sort4_h2(bh);
    h2 yv = bh[0] * uh(wtab[1024 + (c << 2)]);
#pragma unroll
    for (int k = 1; k < 4; k++) yv = bh[k] * uh(wtab[1024 + (c << 2) + k]) + yv;
    float zx = fmaf((float)yv.x, bsc, bbi);
    float zy = fmaf((float)yv.y, bsc, bbi);
    float sx = zx / (1.f + __expf(-zx));
    float sy = zy / (1.f + __expf(-zy));
    return __builtin_bit_cast(unsigned, __floats2half2_rn(sx, sy));
}

__device__ __forceinline__ void conv_group(const unsigned* lxh, unsigned* convt,
                                           const unsigned* dwc, int ty0, int tx0, int u) {
    int row = u / 20;
    int g   = u - row * 20;
    h2 a7A = {0, 0}, a7B = {0, 0}, a5A = {0, 0}, a5B = {0, 0};
    h2 a3A = {0, 0}, a3B = {0, 0}, a1A = {0, 0}, a1B = {0, 0};
#pragma unroll
    for (int a = 0; a < 7; a++) {
        const unsigned* rp = lxh + (row + a) * LXS + 2 * g;
        uint2 w0 = *(const uint2*)rp;
        uint2 w1 = *(const uint2*)(rp + 2);
        uint2 w2 = *(const uint2*)(rp + 4);
        unsigned u0 = w0.x, u1 = w0.y, u2 = w1.x, u3 = w1.y, u4 = w2.x;
        h2 E[9] = {uh(u0), uh(algn(u0, u1)), uh(u1), uh(algn(u1, u2)),
                   uh(u2), uh(algn(u2, u3)), uh(u3), uh(algn(u3, u4)), uh(u4)};
#pragma unroll
        for (int b = 0; b < 7; b++) {
            h2 wv = uh(dwc[a * 7 + b]);
            a7A = E[b] * wv + a7A;  a7B = E[b + 2] * wv + a7B;
        }
        if (a >= 1 && a <= 5) {
#pragma unroll
            for (int b = 0; b < 5; b++) {
                h2 wv = uh(dwc[49 + (a - 1) * 5 + b]);
                a5A = E[b + 1] * wv + a5A;  a5B = E[b + 3] * wv + a5B;
            }
        }
        if (a >= 2 && a <= 4) {
#pragma unroll
            for (int b = 0; b < 3; b++) {
                h2 wv = uh(dwc[74 + (a - 2) * 3 + b]);
                a3A = E[b + 2] * wv + a3A;  a3B = E[b + 4] * wv + a3B;
            }
        }
        if (a == 3) {
            h2 wv = uh(dwc[83]);
            a1A = E[3] * wv;  a1B = E[5] * wv;
        }
    }
    int iy = ty0 - 7 + row;
    bool rin = (unsigned)iy < 256u;
    int ix0 = tx0 - 7 + 4 * g;
    unsigned mA = (rin && (unsigned)ix0 < 256u ? 0x0000FFFFu : 0u)
                | (rin && (unsigned)(ix0 + 1) < 256u ? 0xFFFF0000u : 0u);
    unsigned mB = (rin && (unsigned)(ix0 + 2) < 256u ? 0x0000FFFFu : 0u)
                | (rin && (unsigned)(ix0 + 3) < 256u ? 0xFFFF0000u : 0u);
    int o = row * CTS + 2 * g;
    uint2 s3 = {hu(a3A + uh(dwc[85])) & mA, hu(a3B + uh(dwc[85])) & mB};
    uint2 s7 = {hu(a7A + uh(dwc[87])) & mA, hu(a7B + uh(dwc[87])) & mB};
    *(uint2*)&convt[CTP + o]     = s3;
    *(uint2*)&convt[3 * CTP + o] = s7;
    convt[o + 1]                 = hu(a1A + uh(dwc[84])) & mA;
    convt[o + 2]                 = hu(a1B + uh(dwc[84])) & mB;
    convt[2 * CTP + o + 1]       = hu(a5A + uh(dwc[86])) & mA;
    convt[2 * CTP + o + 2]       = hu(a5B + uh(dwc[86])) & mB;
}

__global__ __launch_bounds__(1024, 8) void k_fused(const __half* __restrict__ xh,
    const unsigned* __restrict__ wtab,
    const float* __restrict__ bns, const float* __restrict__ bnb,
    __half* __restrict__ y16) {

    const int by  = blockIdx.y;                  // b*16 + c
    const int c   = by & 15;
    const int ty0 = (blockIdx.x >> 2) * 64;
    const int tx0 = (blockIdx.x & 3) * 64;
    const int tid = threadIdx.x;

    __shared__ unsigned lxh[84 * LXS];           // fp16 x-tile, rows ty0-10..+73
    __shared__ unsigned convt[4 * CTP];          // conv planes, rows ty0-7..+70

    // ---- stage: 84 rows x 21 uint2 (b64 LDS writes), 2 explicit iterations ----
    {
        const unsigned* xp32 = (const unsigned*)(xh + (size_t)by * HW);
#pragma unroll
        for (int it = 0; it < 2; it++) {
            int t = tid + it * 1024;
            if (it == 0 || t < 84 * 21) {
                int r = t / 21, j = t - r * 21;
                int gy = ty0 - 10 + r;
                int gp = tx0 - 10 + 4 * j;
                unsigned v0 = 0, v1 = 0;
                if ((unsigned)gy < 256u) {
                    const unsigned* rp = xp32 + (gy << 7);
                    if ((unsigned)gp < 256u)       v0 = rp[gp >> 1];
                    if ((unsigned)(gp + 2) < 256u) v1 = rp[(gp >> 1) + 1];
                }
                uint2 st = {v0, v1};
                *(uint2*)&lxh[r * LXS + 2 * j] = st;
            }
        }
    }
    __syncthreads();

    // ---- depthwise convs: 78 rows x 20 groups = 1560, 2 explicit iterations ----
    {
        const unsigned* dwc = wtab + 2048 + c * 96;   // block-uniform
        conv_group(lxh, convt, dwc, ty0, tx0, tid);
        if (tid + 1024 < 78 * 20)
            conv_group(lxh, convt, dwc, ty0, tx0, tid + 1024);
    }
    __syncthreads();

    // ---- machinery: one 4-px group per thread, b64 spans ----
    const int R = tid >> 4;                      // 0..63
    const int g = tid & 15;                      // px 4g..4g+3

    h2 bhA[4], bhB[4];
    branch_pair<1, 1>(convt,           R, g, wtab + ((c << 2) + 0) * 16, &bhA[0], &bhB[0]);
    branch_pair<3, 0>(convt + CTP,     R, g, wtab + ((c << 2) + 1) * 16, &bhA[1], &bhB[1]);
    branch_pair<5, 1>(convt + 2 * CTP, R, g, wtab + ((c << 2) + 2) * 16, &bhA[2], &bhB[2]);
    branch_pair<7, 0>(convt + 3 * CTP, R, g, wtab + ((c << 2) + 3) * 16, &bhA[3], &bhB[3]);

    const float bsc = bns[c], bbi = bnb[c];
    unsigned r0 = tail_px(bhA, wtab, c, bsc, bbi);
    unsigned r1 = tail_px(bhB, wtab, c, bsc, bbi);
    uint2 st = {r0, r1};
    *(uint2*)&y16[(size_t)by * HW + (ty0 + R) * 256 + tx0 + 4 * g] = st;
}

// ---------------- K3: final 1x1 16 -> 1 + sigmoid, 4 px/thread ----------------
__global__ __launch_bounds__(256) void k_final(const __half* __restrict__ y16,
                                               const float* __restrict__ fw,
                                               const float* __restrict__ fb,
                                               float* __restrict__ out) {
    long t  = (long)blockIdx.x * 256 + threadIdx.x;   // quad index, 0..131071
    long p0 = t * 4;
    int  b  = (int)(p0 >> 16);
    int  hw = (int)(p0 & 65535);

    float bv = fb[0];
    float a0 = bv, a1 = bv, a2 = bv, a3 = bv;
#pragma unroll
    for (int cc = 0; cc < 16; cc++) {
        uint2 u = *(const uint2*)(y16 + (size_t)(b * 16 + cc) * HW + hw);   // b64
        float2 v0 = __half22float2(__builtin_bit_cast(__half2, u.x));
        float2 v1 = __half22float2(__builtin_bit_cast(__half2, u.y));
        float wv = fw[cc];
        a0 = fmaf(v0.x, wv, a0);
        a1 = fmaf(v0.y, wv, a1);
        a2 = fmaf(v1.x, wv, a2);
        a3 = fmaf(v1.y, wv, a3);
    }
    float4 r;
    r.x = 1.f / (1.f + __expf(-a0));
    r.y = 1.f / (1.f + __expf(-a1));
    r.z = 1.f / (1.f + __expf(-a2));
    r.w = 1.f / (1.f + __expf(-a3));
    *(float4*)(out + p0) = r;
}

extern "C" void kernel_launch(void* const* d_in, const int* in_sizes, int n_in,
                              void* d_out, int out_size, void* d_ws, size_t ws_size,
                              hipStream_t stream) {
    (void)in_sizes; (void)n_in; (void)out_size; (void)ws_size;
    const float* cen   = (const float*)d_in[0];
    // d_in[1] = mas (unused by the reference)
    const float* in_w  = (const float*)d_in[2];
    const float* in_b  = (const float*)d_in[3];
    const float* dw_w1 = (const float*)d_in[4];
    const float* dw_b1 = (const float*)d_in[5];
    const float* dw_w3 = (const float*)d_in[6];
    const float* dw_b3 = (const float*)d_in[7];
    const float* dw_w5 = (const float*)d_in[8];
    const float* dw_b5 = (const float*)d_in[9];
    const float* dw_w7 = (const float*)d_in[10];
    const float* dw_b7 = (const float*)d_in[11];
    const float* l1w   = (const float*)d_in[12];
    const float* l1b   = (const float*)d_in[13];
    const float* l2w   = (const float*)d_in[14];
    const float* l2b   = (const float*)d_in[15];
    const float* bw    = (const float*)d_in[16];
    const float* bns   = (const float*)d_in[17];
    const float* bnb   = (const float*)d_in[18];
    const float* fw    = (const float*)d_in[19];
    const float* fb    = (const float*)d_in[20];

    // workspace: xh (16.78 MB) | wtab (16 KB) | wtf (8 KB) | y16 (16.78 MB)
    __half*   xh   = (__half*)d_ws;
    unsigned* wtab = (unsigned*)((char*)d_ws + (size_t)16777216);
    float*    wtf  = (float*)((char*)d_ws + (size_t)16777216 + 16384);
    __half*   y16  = (__half*)((char*)d_ws + (size_t)16777216 + 16384 + 8192);
    float*    out  = (float*)d_out;

    k_pack<<<1, 256, 0, stream>>>(l1w, l1b, l2w, l2b, bw,
                                  dw_w1, dw_b1, dw_w3, dw_b3,
                                  dw_w5, dw_b5, dw_w7, dw_b7, in_w, in_b, wtab);
    k_inconv<<<1024, 256, 0, stream>>>(cen, wtf, xh);
    k_fused<<<dim3(16, 128), 1024, 0, stream>>>(xh, wtab, bns, bnb, y16);
    k_final<<<512, 256, 0, stream>>>(y16, fw, fb, out);
}

// Round 9
// 325.182 us; speedup vs baseline: 1.1542x; 1.0224x over previous
//
#include <hip/hip_runtime.h>
#include <hip/hip_fp16.h>
#include <math.h>

#define HW 65536               // 256*256

typedef float v2f __attribute__((ext_vector_type(2), aligned(8)));
typedef _Float16 h2 __attribute__((ext_vector_type(2)));

__device__ __forceinline__ h2 uh(unsigned u) { return __builtin_bit_cast(h2, u); }
__device__ __forceinline__ unsigned hu(h2 v) { return __builtin_bit_cast(unsigned, v); }
__device__ __forceinline__ unsigned algn(unsigned lo, unsigned hi) {
    return (lo >> 16) | (hi << 16);          // v_alignbit_b32
}

#define CEH(a, b) { h2 _t = __builtin_elementwise_min(a, b); \
                    b = __builtin_elementwise_max(a, b); a = _t; }

__device__ __forceinline__ void sort8_h2(h2* v) {
    CEH(v[0], v[1]); CEH(v[2], v[3]); CEH(v[4], v[5]); CEH(v[6], v[7]);
    CEH(v[0], v[2]); CEH(v[1], v[3]); CEH(v[4], v[6]); CEH(v[5], v[7]);
    CEH(v[1], v[2]); CEH(v[5], v[6]); CEH(v[0], v[4]); CEH(v[3], v[7]);
    CEH(v[1], v[5]); CEH(v[2], v[6]);
    CEH(v[1], v[4]); CEH(v[3], v[6]);
    CEH(v[2], v[4]); CEH(v[3], v[5]);
    CEH(v[3], v[4]);
}
__device__ __forceinline__ void sort4_h2(h2* v) {
    CEH(v[0], v[1]); CEH(v[2], v[3]); CEH(v[0], v[2]); CEH(v[1], v[3]); CEH(v[1], v[2]);
}

// ---------------- K0: pack weights (unchanged from R8) ----------------
__global__ __launch_bounds__(256) void k_pack(const float* __restrict__ l1w,
                                              const float* __restrict__ l1b,
                                              const float* __restrict__ l2w,
                                              const float* __restrict__ l2b,
                                              const float* __restrict__ bw,
                                              const float* __restrict__ dw_w1,
                                              const float* __restrict__ dw_b1,
                                              const float* __restrict__ dw_w3,
                                              const float* __restrict__ dw_b3,
                                              const float* __restrict__ dw_w5,
                                              const float* __restrict__ dw_b5,
                                              const float* __restrict__ dw_w7,
                                              const float* __restrict__ dw_b7,
                                              const float* __restrict__ in_w,
                                              const float* __restrict__ in_b,
                                              unsigned* __restrict__ wtab) {
    for (int t = threadIdx.x; t < 3584; t += 256) {
        float v = 0.f;
        if (t < 1024) {
            int c = t >> 6, i = (t >> 4) & 3, j = t & 15;
            if (j < 3)        v = l1w[i * 64 + c * 4 + j];
            else if (j == 3)  v = 2.f * l1w[i * 64 + c * 4 + 3];
            else if (j == 4)  v = l1b[i * 16 + c];
            else if (j < 13)  v = l2w[i * 128 + c * 8 + (j - 5)];
            else if (j == 13) v = l2b[i * 16 + c];
        } else if (t < 1088) {
            v = bw[t - 1024];
        } else if (t >= 2048) {
            int c = (t - 2048) / 96, j = (t - 2048) - c * 96;
            if (j < 49)       v = dw_w7[c * 49 + j];
            else if (j < 74)  v = dw_w5[c * 25 + (j - 49)];
            else if (j < 83)  v = dw_w3[c * 9 + (j - 74)];
            else if (j == 83) v = dw_w1[c];
            else if (j == 84) v = dw_b1[c];
            else if (j == 85) v = dw_b3[c];
            else if (j == 86) v = dw_b5[c];
            else if (j == 87) v = dw_b7[c];
        }
        unsigned hs = (unsigned)__half_as_ushort(__float2half(v));
        wtab[t] = hs * 0x10001u;
    }
    float* wtf = (float*)(wtab + 4096);
    for (int t = threadIdx.x; t < 1040; t += 256) {
        wtf[t] = (t < 1024) ? in_w[(t & 15) * 64 + (t >> 4)] : in_b[t - 1024];
    }
}

// ---------------- K1: in_conv (unchanged from R8) ----------------
__global__ __launch_bounds__(256) void k_inconv(const float* __restrict__ cen,
                                                const float* __restrict__ wtf,
                                                __half* __restrict__ xh) {
    int pr = blockIdx.x * 256 + threadIdx.x;
    int b_ = pr >> 15;
    int hw = (pr & 32767) * 2;
    const float* src = cen + (size_t)(b_ * 64) * HW + hw;

    v2f acc[16];
#pragma unroll
    for (int o = 0; o < 16; o++) { float bv = wtf[1024 + o]; v2f t = {bv, bv}; acc[o] = t; }

#pragma unroll 8
    for (int i = 0; i < 64; i++) {
        v2f xv = *(const v2f*)(src + (size_t)i * HW);
#pragma unroll
        for (int o = 0; o < 16; o++)
            acc[o] += xv * wtf[i * 16 + o];
    }
    __half* dst = xh + (size_t)(b_ * 16) * HW + hw;
#pragma unroll
    for (int o = 0; o < 16; o++)
        *(__half2*)(dst + (size_t)o * HW) = __floats2half2_rn(acc[o].x, acc[o].y);
}

// ---------------- K2: FUSED ----------------
#define LXS 44           // lxh dwords/row, 42 used
#define CTS 42           // convt dwords/row, 40/41 used
#define CTP (78 * CTS)   // convt plane stride

// machinery: single base, all-constexpr non-negative offsets (fold into ds_read offset:)
template<int S, int PAD, int PL>
__device__ __forceinline__ void branch_pair(const unsigned* b3, const unsigned* wt,
                                            h2* outA, h2* outB) {
    constexpr int D0  = (7 - S) / 2 + PAD;       // even
    constexpr int TOP = PL * CTP + (7 - S) * CTS + D0;
    constexpr int MID = PL * CTP + 7 * CTS + D0;
    constexpr int BOT = PL * CTP + (7 + S) * CTS + D0;
    constexpr int L   = (S + 3) / 2;
    unsigned ut[2 * L], um[2 * L], ub[2 * L];
#pragma unroll
    for (int k = 0; k < L; k++) {
        *(uint2*)&ut[2 * k] = *(const uint2*)(b3 + TOP + 2 * k);   // ds_read_b64 offset:
        *(uint2*)&um[2 * k] = *(const uint2*)(b3 + MID + 2 * k);
        *(uint2*)&ub[2 * k] = *(const uint2*)(b3 + BOT + 2 * k);
    }
#pragma unroll
    for (int dw = 0; dw < 2; dw++) {             // pair A (px 4g,4g+1), pair B (+2,+3)
        h2 n0 = uh(ut[dw]);
        h2 n1 = uh(algn(ut[(S - 1) / 2 + dw], ut[(S + 1) / 2 + dw]));
        h2 n2 = uh(ut[S + dw]);
        h2 n7 = uh(um[dw]);
        h2 ct = uh(algn(um[(S - 1) / 2 + dw], um[(S + 1) / 2 + dw]));
        h2 n3 = uh(um[S + dw]);
        h2 n6 = uh(ub[dw]);
        h2 n5 = uh(algn(ub[(S - 1) / 2 + dw], ub[(S + 1) / 2 + dw]));
        h2 n4 = uh(ub[S + dw]);

        h2 T[8];
        T[0] = ct - n0; T[1] = ct - n1; T[2] = ct - n2; T[3] = ct - n3;
        T[4] = ct - n4; T[5] = ct - n5; T[6] = ct - n6; T[7] = ct - n7;
        h2 Sm[4];
#pragma unroll
        for (int k = 0; k < 4; k++) Sm[k] = T[k] + T[k + 4];

        h2 w10 = uh(wt[0]), w11 = uh(wt[1]), w12 = uh(wt[2]);
        h2 w13x2 = uh(wt[3]), bb1 = uh(wt[4]);

        h2 R4[4];
#pragma unroll
        for (int mm = 0; mm < 4; mm++) {
            h2 r = Sm[(mm + 2) & 3] * w12 + bb1;
            r = Sm[(mm + 3) & 3] * w11 + r;
            r = Sm[(mm + 1) & 3] * w10 + r;
            R4[mm] = r;
        }
        h2 h8[8];
#pragma unroll
        for (int k = 0; k < 8; k++)
            h8[k] = (T[(k + 4) & 7] * w13x2 + R4[k & 3]) * T[k];
        sort8_h2(h8);

        h2 acc = uh(wt[13]);
#pragma unroll
        for (int k = 0; k < 8; k++) acc += h8[k] * uh(wt[5 + k]);
        if (dw == 0) *outA = acc; else *outB = acc;
    }
}

__device__ __forceinline__ unsigned tail_px(h2* bh, const unsigned* __restrict__ wtab,
                                            int c, float bsc, float bbi) {
    sort4_h2(bh);
    h2 yv = bh[0] * uh(wtab[1024 + (c << 2)]);
#pragma unroll
    for (int k = 1; k < 4; k++) yv = bh[k] * uh(wtab[1024 + (c << 2) + k]) + yv;
    float zx = fmaf((float)yv.x, bsc, bbi);
    float zy = fmaf((float)yv.y, bsc, bbi);
    float sx = zx / (1.f + __expf(-zx));
    float sy = zy / (1.f + __expf(-zy));
    return __builtin_bit_cast(unsigned, __floats2half2_rn(sx, sy));
}

__device__ __forceinline__ void store_crow(unsigned* convt, int ty0, int tx0,
                                           int row, int g, const unsigned* dwc,
                                           h2 a1A, h2 a1B, h2 a3A, h2 a3B,
                                           h2 a5A, h2 a5B, h2 a7A, h2 a7B) {
    int iy = ty0 - 7 + row;
    bool rin = (unsigned)iy < 256u;
    int ix0 = tx0 - 7 + 4 * g;
    unsigned mA = (rin && (unsigned)ix0 < 256u ? 0x0000FFFFu : 0u)
                | (rin && (unsigned)(ix0 + 1) < 256u ? 0xFFFF0000u : 0u);
    unsigned mB = (rin && (unsigned)(ix0 + 2) < 256u ? 0x0000FFFFu : 0u)
                | (rin && (unsigned)(ix0 + 3) < 256u ? 0xFFFF0000u : 0u);
    int o = row * CTS + 2 * g;
    uint2 s3 = {hu(a3A + uh(dwc[85])) & mA, hu(a3B + uh(dwc[85])) & mB};
    uint2 s7 = {hu(a7A + uh(dwc[87])) & mA, hu(a7B + uh(dwc[87])) & mB};
    *(uint2*)&convt[CTP + o]     = s3;
    *(uint2*)&convt[3 * CTP + o] = s7;
    convt[o + 1]                 = hu(a1A + uh(dwc[84])) & mA;
    convt[o + 2]                 = hu(a1B + uh(dwc[84])) & mB;
    convt[2 * CTP + o + 1]       = hu(a5A + uh(dwc[86])) & mA;
    convt[2 * CTP + o + 2]       = hu(a5B + uh(dwc[86])) & mB;
}

__global__ __launch_bounds__(1024, 8) void k_fused(const __half* __restrict__ xh,
    const unsigned* __restrict__ wtab,
    const float* __restrict__ bns, const float* __restrict__ bnb,
    __half* __restrict__ y16) {

    const int by  = blockIdx.y;                  // b*16 + c
    const int c   = by & 15;
    const int ty0 = (blockIdx.x >> 2) * 64;
    const int tx0 = (blockIdx.x & 3) * 64;
    const int tid = threadIdx.x;

    __shared__ __align__(16) unsigned lxh[84 * LXS];    // fp16 x-tile, rows ty0-10..+73
    __shared__ __align__(16) unsigned convt[4 * CTP];   // conv planes, rows ty0-7..+70

    // ---- stage: 84 rows x 21 uint2 (b64 LDS writes) ----
    {
        const unsigned* xp32 = (const unsigned*)(xh + (size_t)by * HW);
#pragma unroll
        for (int it = 0; it < 2; it++) {
            int t = tid + it * 1024;
            if (it == 0 || t < 84 * 21) {
                int r = t / 21, j = t - r * 21;
                int gy = ty0 - 10 + r;
                int gp = tx0 - 10 + 4 * j;
                unsigned v0 = 0, v1 = 0;
                if ((unsigned)gy < 256u) {
                    const unsigned* rp = xp32 + (gy << 7);
                    if ((unsigned)gp < 256u)       v0 = rp[gp >> 1];
                    if ((unsigned)(gp + 2) < 256u) v1 = rp[(gp >> 1) + 1];
                }
                uint2 st = {v0, v1};
                *(uint2*)&lxh[r * LXS + 2 * j] = st;
            }
        }
    }
    __syncthreads();

    // ---- depthwise convs: 39 row-pairs x 20 col-groups = 780 units, single pass ----
    {
        const unsigned* dwc = wtab + 2048 + c * 96;   // block-uniform -> s_load
        if (tid < 780) {
            int rp_ = tid / 20, g = tid - rp_ * 20;
            int r0 = rp_ * 2;                         // output rows r0, r0+1
            h2 z = {0, 0};
            h2 a7A0 = z, a7B0 = z, a5A0 = z, a5B0 = z, a3A0 = z, a3B0 = z, a1A0 = z, a1B0 = z;
            h2 a7A1 = z, a7B1 = z, a5A1 = z, a5B1 = z, a3A1 = z, a3B1 = z, a1A1 = z, a1B1 = z;
#pragma unroll
            for (int a = 0; a < 8; a++) {
                const unsigned* rrp = lxh + (r0 + a) * LXS + 2 * g;
                uint2 w0 = *(const uint2*)rrp;
                uint2 w1 = *(const uint2*)(rrp + 2);
                uint2 w2 = *(const uint2*)(rrp + 4);
                unsigned u0 = w0.x, u1 = w0.y, u2 = w1.x, u3 = w1.y, u4 = w2.x;
                h2 E[9] = {uh(u0), uh(algn(u0, u1)), uh(u1), uh(algn(u1, u2)),
                           uh(u2), uh(algn(u2, u3)), uh(u3), uh(algn(u3, u4)), uh(u4)};
                if (a < 7) {                          // taps for output row r0
#pragma unroll
                    for (int b = 0; b < 7; b++) {
                        h2 wv = uh(dwc[a * 7 + b]);
                        a7A0 = E[b] * wv + a7A0;  a7B0 = E[b + 2] * wv + a7B0;
                    }
                    if (a >= 1 && a <= 5) {
#pragma unroll
                        for (int b = 0; b < 5; b++) {
                            h2 wv = uh(dwc[49 + (a - 1) * 5 + b]);
                            a5A0 = E[b + 1] * wv + a5A0;  a5B0 = E[b + 3] * wv + a5B0;
                        }
                    }
                    if (a >= 2 && a <= 4) {
#pragma unroll
                        for (int b = 0; b < 3; b++) {
                            h2 wv = uh(dwc[74 + (a - 2) * 3 + b]);
                            a3A0 = E[b + 2] * wv + a3A0;  a3B0 = E[b + 4] * wv + a3B0;
                        }
                    }
                    if (a == 3) {
                        h2 wv = uh(dwc[83]);
                        a1A0 = E[3] * wv;  a1B0 = E[5] * wv;
                    }
                }
                if (a >= 1) {                         // taps for output row r0+1
                    const int ar = a - 1;
#pragma unroll
                    for (int b = 0; b < 7; b++) {
                        h2 wv = uh(dwc[ar * 7 + b]);
                        a7A1 = E[b] * wv + a7A1;  a7B1 = E[b + 2] * wv + a7B1;
                    }
                    if (ar >= 1 && ar <= 5) {
#pragma unroll
                        for (int b = 0; b < 5; b++) {
                            h2 wv = uh(dwc[49 + (ar - 1) * 5 + b]);
                            a5A1 = E[b + 1] * wv + a5A1;  a5B1 = E[b + 3] * wv + a5B1;
                        }
                    }
                    if (ar >= 2 && ar <= 4) {
#pragma unroll
                        for (int b = 0; b < 3; b++) {
                            h2 wv = uh(dwc[74 + (ar - 2) * 3 + b]);
                            a3A1 = E[b + 2] * wv + a3A1;  a3B1 = E[b + 4] * wv + a3B1;
                        }
                    }
                    if (ar == 3) {
                        h2 wv = uh(dwc[83]);
                        a1A1 = E[3] * wv;  a1B1 = E[5] * wv;
                    }
                }
            }
            store_crow(convt, ty0, tx0, r0,     g, dwc, a1A0, a1B0, a3A0, a3B0, a5A0, a5B0, a7A0, a7B0);
            store_crow(convt, ty0, tx0, r0 + 1, g, dwc, a1A1, a1B1, a3A1, a3B1, a5A1, a5B1, a7A1, a7B1);
        }
    }
    __syncthreads();

    // ---- machinery: one 4-px group per thread, single-base constexpr-offset reads ----
    const int R = tid >> 4;                      // 0..63
    const int g = tid & 15;                      // px 4g..4g+3
    const unsigned* b3 = convt + R * CTS + 2 * g;

    h2 bhA[4], bhB[4];
    branch_pair<1, 1, 0>(b3, wtab + ((c << 2) + 0) * 16, &bhA[0], &bhB[0]);
    branch_pair<3, 0, 1>(b3, wtab + ((c << 2) + 1) * 16, &bhA[1], &bhB[1]);
    branch_pair<5, 1, 2>(b3, wtab + ((c << 2) + 2) * 16, &bhA[2], &bhB[2]);
    branch_pair<7, 0, 3>(b3, wtab + ((c << 2) + 3) * 16, &bhA[3], &bhB[3]);

    const float bsc = bns[c], bbi = bnb[c];
    unsigned r0 = tail_px(bhA, wtab, c, bsc, bbi);
    unsigned r1 = tail_px(bhB, wtab, c, bsc, bbi);
    uint2 st = {r0, r1};
    *(uint2*)&y16[(size_t)by * HW + (ty0 + R) * 256 + tx0 + 4 * g] = st;
}

// ---------------- K3: final 1x1 16 -> 1 + sigmoid, 4 px/thread (unchanged) ----------------
__global__ __launch_bounds__(256) void k_final(const __half* __restrict__ y16,
                                               const float* __restrict__ fw,
                                               const float* __restrict__ fb,
                                               float* __restrict__ out) {
    long t  = (long)blockIdx.x * 256 + threadIdx.x;
    long p0 = t * 4;
    int  b  = (int)(p0 >> 16);
    int  hw = (int)(p0 & 65535);

    float bv = fb[0];
    float a0 = bv, a1 = bv, a2 = bv, a3 = bv;
#pragma unroll
    for (int cc = 0; cc < 16; cc++) {
        uint2 u = *(const uint2*)(y16 + (size_t)(b * 16 + cc) * HW + hw);
        float2 v0 = __half22float2(__builtin_bit_cast(__half2, u.x));
        float2 v1 = __half22float2(__builtin_bit_cast(__half2, u.y));
        float wv = fw[cc];
        a0 = fmaf(v0.x, wv, a0);
        a1 = fmaf(v0.y, wv, a1);
        a2 = fmaf(v1.x, wv, a2);
        a3 = fmaf(v1.y, wv, a3);
    }
    float4 r;
    r.x = 1.f / (1.f + __expf(-a0));
    r.y = 1.f / (1.f + __expf(-a1));
    r.z = 1.f / (1.f + __expf(-a2));
    r.w = 1.f / (1.f + __expf(-a3));
    *(float4*)(out + p0) = r;
}

extern "C" void kernel_launch(void* const* d_in, const int* in_sizes, int n_in,
                              void* d_out, int out_size, void* d_ws, size_t ws_size,
                              hipStream_t stream) {
    (void)in_sizes; (void)n_in; (void)out_size; (void)ws_size;
    const float* cen   = (const float*)d_in[0];
    // d_in[1] = mas (unused by the reference)
    const float* in_w  = (const float*)d_in[2];
    const float* in_b  = (const float*)d_in[3];
    const float* dw_w1 = (const float*)d_in[4];
    const float* dw_b1 = (const float*)d_in[5];
    const float* dw_w3 = (const float*)d_in[6];
    const float* dw_b3 = (const float*)d_in[7];
    const float* dw_w5 = (const float*)d_in[8];
    const float* dw_b5 = (const float*)d_in[9];
    const float* dw_w7 = (const float*)d_in[10];
    const float* dw_b7 = (const float*)d_in[11];
    const float* l1w   = (const float*)d_in[12];
    const float* l1b   = (const float*)d_in[13];
    const float* l2w   = (const float*)d_in[14];
    const float* l2b   = (const float*)d_in[15];
    const float* bw    = (const float*)d_in[16];
    const float* bns   = (const float*)d_in[17];
    const float* bnb   = (const float*)d_in[18];
    const float* fw    = (const float*)d_in[19];
    const float* fb    = (const float*)d_in[20];

    // workspace: xh (16.78 MB) | wtab (16 KB) | wtf (8 KB) | y16 (16.78 MB)
    __half*   xh   = (__half*)d_ws;
    unsigned* wtab = (unsigned*)((char*)d_ws + (size_t)16777216);
    float*    wtf  = (float*)((char*)d_ws + (size_t)16777216 + 16384);
    __half*   y16  = (__half*)((char*)d_ws + (size_t)16777216 + 16384 + 8192);
    float*    out  = (float*)d_out;

    k_pack<<<1, 256, 0, stream>>>(l1w, l1b, l2w, l2b, bw,
                                  dw_w1, dw_b1, dw_w3, dw_b3,
                                  dw_w5, dw_b5, dw_w7, dw_b7, in_w, in_b, wtab);
    k_inconv<<<1024, 256, 0, stream>>>(cen, wtf, xh);
    k_fused<<<dim3(16, 128), 1024, 0, stream>>>(xh, wtab, bns, bnb, y16);
    k_final<<<512, 256, 0, stream>>>(y16, fw, fb, out);
}